// Round 1
// baseline (1125.078 us; speedup 1.0000x reference)
//
#include <hip/hip_runtime.h>
#include <hip/hip_bf16.h>

#define TPB 256

// ---------------- CSR build ----------------
__global__ void k_count(const int* __restrict__ ei, int E, int* __restrict__ cnt){
  int e = blockIdx.x*blockDim.x + threadIdx.x;
  if(e < E) atomicAdd(&cnt[ei[E + e]], 1);   // rows = dst = edge_index[1]
}

__global__ void k_scan(const int* __restrict__ cnt, int n, int* __restrict__ rowptr){
  __shared__ int sh[1024];
  int carry = 0;
  if(threadIdx.x == 0) rowptr[0] = 0;
  for(int base = 0; base < n; base += 1024){
    int i = base + (int)threadIdx.x;
    int v = (i < n) ? cnt[i] : 0;
    sh[threadIdx.x] = v;
    __syncthreads();
    for(int off = 1; off < 1024; off <<= 1){
      int t = (threadIdx.x >= (unsigned)off) ? sh[threadIdx.x - off] : 0;
      __syncthreads();
      sh[threadIdx.x] += t;
      __syncthreads();
    }
    if(i < n) rowptr[i+1] = carry + sh[threadIdx.x];
    carry += sh[1023];
    __syncthreads();
  }
}

__global__ void k_fill(const int* __restrict__ ei, int E, const int* __restrict__ rowptr,
                       int* __restrict__ fill, int* __restrict__ colidx){
  int e = blockIdx.x*blockDim.x + threadIdx.x;
  if(e >= E) return;
  int d = ei[E + e], s = ei[e];
  int p = rowptr[d] + atomicAdd(&fill[d], 1);
  colidx[p] = s;
}

__global__ void k_dinv(const int* __restrict__ cnt, int n, float* __restrict__ dinv){
  int i = blockIdx.x*blockDim.x + threadIdx.x;
  if(i < n) dinv[i] = rsqrtf((float)cnt[i] + 2.0f);   // deg = rowsum(A)+2
}

// out[i][c] = dinv[i] * sum_d h[i][d]*W[d][c]
__global__ void k_mm_dinv(const float* __restrict__ h, const float* __restrict__ W,
                          const float* __restrict__ dinv, float* __restrict__ out,
                          int n, int cin, int cout){
  int t = blockIdx.x*blockDim.x + threadIdx.x;
  if(t >= n*cout) return;
  int i = t / cout, c = t % cout;
  float s = 0.f;
  for(int d = 0; d < cin; ++d) s += h[i*cin + d] * W[d*cout + c];
  out[t] = dinv[i] * s;
}

// y[i][c] = dinv[i]*( sum_{e:dst=i} xwd[src][c] + 2*xwd[i][c] ) + b[c]
template<int C, bool RELU>
__global__ void k_csr_gcn(const int* __restrict__ rowptr, const int* __restrict__ colidx,
                          const float* __restrict__ xwd, const float* __restrict__ dinv,
                          const float* __restrict__ bias, float* __restrict__ out, int n){
  int t = blockIdx.x*blockDim.x + threadIdx.x;
  if(t >= n*C) return;
  int i = t / C, c = t % C;
  float acc = 2.0f * xwd[i*C + c];
  int b = rowptr[i], e = rowptr[i+1];
  for(int p = b; p < e; ++p) acc += xwd[colidx[p]*C + c];
  float y = dinv[i]*acc + bias[c];
  out[t] = RELU ? fmaxf(y, 0.f) : y;
}

__global__ void k_score(const float* __restrict__ h, const float* __restrict__ p,
                        float* __restrict__ score, int n){
  int i = blockIdx.x*blockDim.x + threadIdx.x;
  if(i >= n) return;
  float nrm = 0.f, s = 0.f;
  for(int c = 0; c < 32; ++c){ float pv = p[c]; nrm += pv*pv; s += h[i*32 + c]*pv; }
  score[i] = tanhf(s / sqrtf(nrm));
}

// single-block bitonic sort, descending (score, then lower index first) — matches jax.lax.top_k
__global__ void k_topk(const float* __restrict__ score, int n, int M, int k,
                       int* __restrict__ perm, float* __restrict__ vals, int* __restrict__ rank){
  extern __shared__ unsigned long long key[];
  for(int i = threadIdx.x; i < M; i += blockDim.x){
    unsigned long long kk = 0ull;
    if(i < n){
      unsigned u = __float_as_uint(score[i]);
      u ^= (u & 0x80000000u) ? 0xFFFFFFFFu : 0x80000000u;   // order-preserving map
      kk = ((unsigned long long)u << 32) | (unsigned)(~(unsigned)i);
    }
    key[i] = kk;
  }
  for(int sz = 2; sz <= M; sz <<= 1){
    for(int st = sz >> 1; st > 0; st >>= 1){
      __syncthreads();
      for(int i = threadIdx.x; i < M; i += blockDim.x){
        int j = i ^ st;
        if(j > i){
          unsigned long long a = key[i], b = key[j];
          bool up = ((i & sz) == 0);
          if(up ? (a < b) : (a > b)){ key[i] = b; key[j] = a; }
        }
      }
    }
  }
  __syncthreads();
  for(int i = threadIdx.x; i < k; i += blockDim.x){
    int idx = (int)(~(unsigned)(key[i] & 0xFFFFFFFFull));
    perm[i] = idx;
    vals[i] = score[idx];
    rank[idx] = i;
  }
}

__global__ void k_pool(const float* __restrict__ h, const int* __restrict__ perm,
                       const float* __restrict__ vals, float* __restrict__ out, int k){
  int t = blockIdx.x*blockDim.x + threadIdx.x;
  if(t >= k*32) return;
  int i = t >> 5, c = t & 31;
  out[t] = h[perm[i]*32 + c] * vals[i];
}

// C[rank[d], rank[j]] += A^2 + 2A contributions via 2-path enumeration (exact integer adds)
__global__ void k_twohop0(const int* __restrict__ ei, int E, const int* __restrict__ rowptr,
                          const int* __restrict__ colidx, const int* __restrict__ rank,
                          float* __restrict__ C, int K){
  int e = blockIdx.x*blockDim.x + threadIdx.x;
  if(e >= E) return;
  int d = ei[E + e];
  int rd = rank[d];
  if(rd < 0) return;
  int s = ei[e];
  float* Crow = C + (size_t)rd * K;
  int rs = rank[s];
  if(rs >= 0) atomicAdd(&Crow[rs], 2.0f);            // 2A term
  for(int p = rowptr[s], pe = rowptr[s+1]; p < pe; ++p){
    int r2 = rank[colidx[p]];
    if(r2 >= 0) atomicAdd(&Crow[r2], 1.0f);          // A^2 (2-path) term
  }
}

__global__ void k_zerodiag(float* __restrict__ C, int K){
  int i = blockIdx.x*blockDim.x + threadIdx.x;
  if(i < K) C[(size_t)i*K + i] = 0.f;
}

__global__ void k_rowsum_dinv(const float* __restrict__ C, int n, float* __restrict__ dinv){
  int i = blockIdx.x;
  float s = 0.f;
  for(int j = threadIdx.x; j < n; j += blockDim.x) s += C[(size_t)i*n + j];
  for(int o = 32; o > 0; o >>= 1) s += __shfl_down(s, o, 64);
  __shared__ float sh[4];
  int lane = threadIdx.x & 63, w = threadIdx.x >> 6;
  if(lane == 0) sh[w] = s;
  __syncthreads();
  if(threadIdx.x == 0){
    float t = 0.f;
    for(int q = 0; q < (int)(blockDim.x >> 6); ++q) t += sh[q];
    dinv[i] = rsqrtf(t + 2.0f);
  }
}

template<bool RELU>
__global__ void k_dense_gcn(const float* __restrict__ C, const float* __restrict__ hwd,
                            const float* __restrict__ dinv, const float* __restrict__ bias,
                            float* __restrict__ out, int n){
  int t = blockIdx.x*blockDim.x + threadIdx.x;
  if(t >= n*32) return;
  int i = t >> 5, c = t & 31;
  const float* row = C + (size_t)i*n;
  float acc = 2.0f * hwd[i*32 + c];
  for(int j = 0; j < n; ++j){
    float a = row[j];
    if(a != 0.f) acc += a * hwd[j*32 + c];   // C is ~4% dense; skip loads on zeros
  }
  float y = dinv[i]*acc + bias[c];
  out[t] = RELU ? fmaxf(y, 0.f) : y;
}

// Bp[t][j] = C[t][perm[j]] + (t==perm[j])   (packed B for coalesced two-hop GEMM)
__global__ void k_gather_cols(const float* __restrict__ C, int n, const int* __restrict__ perm,
                              int k, float* __restrict__ Bp){
  int t = blockIdx.x*blockDim.x + threadIdx.x;
  if(t >= n*k) return;
  int tt = t / k, j = t % k;
  int qj = perm[j];
  Bp[t] = C[(size_t)tt*n + qj] + ((tt == qj) ? 1.f : 0.f);
}

// out[i][j] = sum_t (C[qi][t]+(t==qi)) * Bp[t][j],  diag forced 0
__global__ void k_twohop_dense(const float* __restrict__ C, int n, const int* __restrict__ perm,
                               int k, const float* __restrict__ Bp, float* __restrict__ out){
  int t = blockIdx.x*blockDim.x + threadIdx.x;
  if(t >= k*k) return;
  int i = t / k, j = t % k;
  int qi = perm[i];
  const float* ri = C + (size_t)qi*n;
  float s = 0.f;
  for(int tt = 0; tt < n; ++tt){
    float a = ri[tt] + ((tt == qi) ? 1.f : 0.f);
    s += a * Bp[(size_t)tt*k + j];
  }
  out[t] = (i == j) ? 0.f : s;
}

__global__ void k_addup(const float* __restrict__ base, const float* __restrict__ h,
                        const int* __restrict__ rank, float* __restrict__ out, int n){
  int t = blockIdx.x*blockDim.x + threadIdx.x;
  if(t >= n*32) return;
  int i = t >> 5, c = t & 31;
  int r = rank[i];
  out[t] = base[t] + ((r >= 0) ? h[r*32 + c] : 0.f);
}

__global__ void k_bn(float* __restrict__ out, int n, const float* __restrict__ g,
                     const float* __restrict__ b){
  __shared__ float sh[16];
  __shared__ float sval;
  int tid = threadIdx.x, lane = tid & 63, w = tid >> 6;
  int nw = blockDim.x >> 6;
  float s = 0.f;
  for(int i = tid; i < n; i += blockDim.x) s += out[i*4];
  for(int o = 32; o > 0; o >>= 1) s += __shfl_down(s, o, 64);
  if(lane == 0) sh[w] = s;
  __syncthreads();
  if(tid == 0){ float t = 0.f; for(int q = 0; q < nw; ++q) t += sh[q]; sval = t / n; }
  __syncthreads();
  float mean = sval;
  float v = 0.f;
  for(int i = tid; i < n; i += blockDim.x){ float d = out[i*4] - mean; v += d*d; }
  for(int o = 32; o > 0; o >>= 1) v += __shfl_down(v, o, 64);
  __syncthreads();
  if(lane == 0) sh[w] = v;
  __syncthreads();
  if(tid == 0){ float t = 0.f; for(int q = 0; q < nw; ++q) t += sh[q]; sval = t / n; }
  __syncthreads();
  float var = sval;
  float scale = g[0] * rsqrtf(var + 1e-5f);
  float beta = b[0];
  for(int i = tid; i < n; i += blockDim.x){
    float r = scale*(out[i*4] - mean) + beta;
    out[i*4] = 1.f / (1.f + expf(-r));
  }
}

extern "C" void kernel_launch(void* const* d_in, const int* in_sizes, int n_in,
                              void* d_out, int out_size, void* d_ws, size_t ws_size,
                              hipStream_t stream){
  const float* x  =(const float*)d_in[0];
  const int*   ei =(const int*)  d_in[1];
  const float* W0 =(const float*)d_in[2];  const float* b0 =(const float*)d_in[3];
  const float* W1 =(const float*)d_in[4];  const float* b1 =(const float*)d_in[5];
  const float* W2 =(const float*)d_in[6];  const float* b2 =(const float*)d_in[7];
  const float* W3 =(const float*)d_in[8];  const float* b3 =(const float*)d_in[9];
  const float* p0 =(const float*)d_in[10];
  const float* p1 =(const float*)d_in[11];
  const float* p2 =(const float*)d_in[12];
  const float* Wu0=(const float*)d_in[13]; const float* bu0=(const float*)d_in[14];
  const float* Wu1=(const float*)d_in[15]; const float* bu1=(const float*)d_in[16];
  const float* Wu2=(const float*)d_in[17]; const float* bu2=(const float*)d_in[18];
  const float* bng=(const float*)d_in[19]; const float* bnb=(const float*)d_in[20];
  float* out = (float*)d_out;

  const int n0 = in_sizes[0] / 3;       // 6000
  const int E  = in_sizes[1] / 2;       // 96000
  const int K1 = (n0 + 4) / 5;          // 1200
  const int K2 = (K1 + 4) / 5;          // 240
  const int K3 = (K2 + 4) / 5;          // 48

  char* wsp = (char*)d_ws; size_t off = 0;
  auto alloc = [&](size_t bytes)->char*{
    char* p = wsp + off; off = (off + bytes + 255) & ~((size_t)255); return p;
  };

  int*   cnt    = (int*)  alloc((size_t)n0*4);
  int*   rowptr = (int*)  alloc((size_t)(n0+1)*4);
  int*   fill   = (int*)  alloc((size_t)n0*4);
  int*   colidx = (int*)  alloc((size_t)E*4);
  float* dinv0  = (float*)alloc((size_t)n0*4);
  float* xwd0   = (float*)alloc((size_t)n0*32*4);
  float* h0     = (float*)alloc((size_t)n0*32*4);
  float* score  = (float*)alloc((size_t)n0*4);
  int*   perm1  = (int*)  alloc((size_t)K1*4);
  float* vals1  = (float*)alloc((size_t)K1*4);
  int*   rank1  = (int*)  alloc((size_t)n0*4);
  float* h1p    = (float*)alloc((size_t)K1*32*4);
  float* C1     = (float*)alloc((size_t)K1*K1*4);
  float* dinv1  = (float*)alloc((size_t)K1*4);
  float* hwd    = (float*)alloc((size_t)K1*32*4);   // tmp: max(K1*32, n0*4)
  float* h1     = (float*)alloc((size_t)K1*32*4);
  int*   perm2  = (int*)  alloc((size_t)K2*4);
  float* vals2  = (float*)alloc((size_t)K2*4);
  int*   rank2  = (int*)  alloc((size_t)K1*4);
  float* h2p    = (float*)alloc((size_t)K2*32*4);
  float* C2     = (float*)alloc((size_t)K2*K2*4);
  float* dinv2  = (float*)alloc((size_t)K2*4);
  float* h2     = (float*)alloc((size_t)K2*32*4);
  float* Bp     = (float*)alloc((size_t)K1*K2*4);
  int*   perm3  = (int*)  alloc((size_t)K3*4);
  float* vals3  = (float*)alloc((size_t)K3*4);
  int*   rank3  = (int*)  alloc((size_t)K2*4);
  float* h3p    = (float*)alloc((size_t)K3*32*4);
  float* C3     = (float*)alloc((size_t)K3*K3*4);
  float* dinv3  = (float*)alloc((size_t)K3*4);
  float* h3     = (float*)alloc((size_t)K3*32*4);
  float* hu2    = (float*)alloc((size_t)K2*32*4);
  float* hu1    = (float*)alloc((size_t)K1*32*4);
  float* z      = (float*)alloc((size_t)n0*32*4);   // shared z buffer for all up levels

  // per-call zero/flag init (ws is poisoned, not re-zeroed by harness)
  hipMemsetAsync(cnt,  0,    (size_t)n0*4,    stream);
  hipMemsetAsync(fill, 0,    (size_t)n0*4,    stream);
  hipMemsetAsync(rank1,0xFF, (size_t)n0*4,    stream);
  hipMemsetAsync(rank2,0xFF, (size_t)K1*4,    stream);
  hipMemsetAsync(rank3,0xFF, (size_t)K2*4,    stream);
  hipMemsetAsync(C1,   0,    (size_t)K1*K1*4, stream);

  const int gE = (E + TPB - 1) / TPB;
  // ---- CSR + deg ----
  k_count<<<gE, TPB, 0, stream>>>(ei, E, cnt);
  k_scan <<<1, 1024, 0, stream>>>(cnt, n0, rowptr);
  k_fill <<<gE, TPB, 0, stream>>>(ei, E, rowptr, fill, colidx);
  k_dinv <<<(n0+TPB-1)/TPB, TPB, 0, stream>>>(cnt, n0, dinv0);
  // ---- GCN0 (n0, 3->32, relu) ----
  k_mm_dinv<<<(n0*32+TPB-1)/TPB, TPB, 0, stream>>>(x, W0, dinv0, xwd0, n0, 3, 32);
  k_csr_gcn<32,true><<<(n0*32+TPB-1)/TPB, TPB, 0, stream>>>(rowptr, colidx, xwd0, dinv0, b0, h0, n0);
  // ---- pool 1 ----
  k_score<<<(n0+TPB-1)/TPB, TPB, 0, stream>>>(h0, p0, score, n0);
  k_topk <<<1, 1024, 8192*8, stream>>>(score, n0, 8192, K1, perm1, vals1, rank1);
  k_pool <<<(K1*32+TPB-1)/TPB, TPB, 0, stream>>>(h0, perm1, vals1, h1p, K1);
  // ---- two-hop level0 -> C1 (sparse path enumeration) ----
  k_twohop0 <<<gE, TPB, 0, stream>>>(ei, E, rowptr, colidx, rank1, C1, K1);
  k_zerodiag<<<(K1+TPB-1)/TPB, TPB, 0, stream>>>(C1, K1);
  // ---- GCN1 (K1, relu) ----
  k_rowsum_dinv<<<K1, 256, 0, stream>>>(C1, K1, dinv1);
  k_mm_dinv<<<(K1*32+TPB-1)/TPB, TPB, 0, stream>>>(h1p, W1, dinv1, hwd, K1, 32, 32);
  k_dense_gcn<true><<<(K1*32+TPB-1)/TPB, TPB, 0, stream>>>(C1, hwd, dinv1, b1, h1, K1);
  // ---- pool 2 ----
  k_score<<<(K1+TPB-1)/TPB, TPB, 0, stream>>>(h1, p1, score, K1);
  k_topk <<<1, 1024, 2048*8, stream>>>(score, K1, 2048, K2, perm2, vals2, rank2);
  k_pool <<<(K2*32+TPB-1)/TPB, TPB, 0, stream>>>(h1, perm2, vals2, h2p, K2);
  // ---- two-hop level1 -> C2 (gathered dense) ----
  k_gather_cols <<<(K1*K2+TPB-1)/TPB, TPB, 0, stream>>>(C1, K1, perm2, K2, Bp);
  k_twohop_dense<<<(K2*K2+TPB-1)/TPB, TPB, 0, stream>>>(C1, K1, perm2, K2, Bp, C2);
  // ---- GCN2 (K2, relu) ----
  k_rowsum_dinv<<<K2, 256, 0, stream>>>(C2, K2, dinv2);
  k_mm_dinv<<<(K2*32+TPB-1)/TPB, TPB, 0, stream>>>(h2p, W2, dinv2, hwd, K2, 32, 32);
  k_dense_gcn<true><<<(K2*32+TPB-1)/TPB, TPB, 0, stream>>>(C2, hwd, dinv2, b2, h2, K2);
  // ---- pool 3 ----
  k_score<<<(K2+TPB-1)/TPB, TPB, 0, stream>>>(h2, p2, score, K2);
  k_topk <<<1, 1024, 256*8, stream>>>(score, K2, 256, K3, perm3, vals3, rank3);
  k_pool <<<(K3*32+TPB-1)/TPB, TPB, 0, stream>>>(h2, perm3, vals3, h3p, K3);
  // ---- two-hop level2 -> C3 ----
  k_gather_cols <<<(K2*K3+TPB-1)/TPB, TPB, 0, stream>>>(C2, K2, perm3, K3, Bp);
  k_twohop_dense<<<(K3*K3+TPB-1)/TPB, TPB, 0, stream>>>(C2, K2, perm3, K3, Bp, C3);
  // ---- GCN3 (K3, relu) ----
  k_rowsum_dinv<<<K3, 256, 0, stream>>>(C3, K3, dinv3);
  k_mm_dinv<<<(K3*32+TPB-1)/TPB, TPB, 0, stream>>>(h3p, W3, dinv3, hwd, K3, 32, 32);
  k_dense_gcn<true><<<(K3*32+TPB-1)/TPB, TPB, 0, stream>>>(C3, hwd, dinv3, b3, h3, K3);
  // ---- up 0 (level 2, relu) ----
  k_addup<<<(K2*32+TPB-1)/TPB, TPB, 0, stream>>>(h2, h3, rank3, z, K2);
  k_mm_dinv<<<(K2*32+TPB-1)/TPB, TPB, 0, stream>>>(z, Wu0, dinv2, hwd, K2, 32, 32);
  k_dense_gcn<true><<<(K2*32+TPB-1)/TPB, TPB, 0, stream>>>(C2, hwd, dinv2, bu0, hu2, K2);
  // ---- up 1 (level 1, relu) ----
  k_addup<<<(K1*32+TPB-1)/TPB, TPB, 0, stream>>>(h1, hu2, rank2, z, K1);
  k_mm_dinv<<<(K1*32+TPB-1)/TPB, TPB, 0, stream>>>(z, Wu1, dinv1, hwd, K1, 32, 32);
  k_dense_gcn<true><<<(K1*32+TPB-1)/TPB, TPB, 0, stream>>>(C1, hwd, dinv1, bu1, hu1, K1);
  // ---- up 2 (level 0, 32->4, no relu) ----
  k_addup<<<(n0*32+TPB-1)/TPB, TPB, 0, stream>>>(h0, hu1, rank1, z, n0);
  k_mm_dinv<<<(n0*4+TPB-1)/TPB, TPB, 0, stream>>>(z, Wu2, dinv0, hwd, n0, 32, 4);
  k_csr_gcn<4,false><<<(n0*4+TPB-1)/TPB, TPB, 0, stream>>>(rowptr, colidx, hwd, dinv0, bu2, out, n0);
  // ---- final BN + sigmoid on column 0 ----
  k_bn<<<1, 1024, 0, stream>>>(out, n0, bng, bnb);
}

// Round 2
// 520.770 us; speedup vs baseline: 2.1604x; 2.1604x over previous
//
#include <hip/hip_runtime.h>
#include <hip/hip_bf16.h>

#define TPB 256

// ---------------- CSR build (level 0 adjacency) ----------------
__global__ void k_count(const int* __restrict__ ei, int E, int* __restrict__ cnt){
  int e = blockIdx.x*blockDim.x + threadIdx.x;
  if(e < E) atomicAdd(&cnt[ei[E + e]], 1);   // rows = dst = edge_index[1]
}

// single-block scan, IPT elements per thread (1024 threads)
template<int IPT>
__global__ void k_scan(const int* __restrict__ cnt, int n, int* __restrict__ rowptr){
  int tid = threadIdx.x;
  int base = tid * IPT;
  int loc[IPT]; int s = 0;
  #pragma unroll
  for(int q = 0; q < IPT; ++q){ int i = base + q; int v = (i < n) ? cnt[i] : 0; s += v; loc[q] = s; }
  int lane = tid & 63, w = tid >> 6;
  int ss = s;
  #pragma unroll
  for(int o = 1; o < 64; o <<= 1){ int t = __shfl_up(ss, o, 64); if(lane >= o) ss += t; }
  __shared__ int wsum[16];
  if(lane == 63) wsum[w] = ss;
  __syncthreads();
  if(tid < 16){
    int t = wsum[tid];
    for(int o = 1; o < 16; o <<= 1){ int u = __shfl_up(t, o, 64); if(tid >= o) t += u; }
    wsum[tid] = t;
  }
  __syncthreads();
  int excl = ss - s + (w > 0 ? wsum[w-1] : 0);
  if(tid == 0) rowptr[0] = 0;
  #pragma unroll
  for(int q = 0; q < IPT; ++q){ int i = base + q; if(i < n) rowptr[i+1] = excl + loc[q]; }
}

__global__ void k_fill(const int* __restrict__ ei, int E, const int* __restrict__ rowptr,
                       int* __restrict__ fill, int* __restrict__ colidx){
  int e = blockIdx.x*blockDim.x + threadIdx.x;
  if(e >= E) return;
  int d = ei[E + e], s = ei[e];
  int p = rowptr[d] + atomicAdd(&fill[d], 1);
  colidx[p] = s;
}

__global__ void k_dinv(const int* __restrict__ cnt, int n, float* __restrict__ dinv){
  int i = blockIdx.x*blockDim.x + threadIdx.x;
  if(i < n) dinv[i] = rsqrtf((float)cnt[i] + 2.0f);   // deg = rowsum(A)+2
}

// out[i][c] = dinv[i] * sum_d h[i][d]*W[d][c]
__global__ void k_mm_dinv(const float* __restrict__ h, const float* __restrict__ W,
                          const float* __restrict__ dinv, float* __restrict__ out,
                          int n, int cin, int cout){
  int t = blockIdx.x*blockDim.x + threadIdx.x;
  if(t >= n*cout) return;
  int i = t / cout, c = t % cout;
  float s = 0.f;
  for(int d = 0; d < cin; ++d) s += h[i*cin + d] * W[d*cout + c];
  out[t] = dinv[i] * s;
}

// fused unpool-add + weight GEMM: out = dinv[i] * ((base + scatter(h))·W)
template<int COUT>
__global__ void k_addup_mm(const float* __restrict__ base, const float* __restrict__ h,
                           const int* __restrict__ rank, const float* __restrict__ W,
                           const float* __restrict__ dinv, float* __restrict__ out, int n){
  int t = blockIdx.x*blockDim.x + threadIdx.x;
  if(t >= n*COUT) return;
  int i = t / COUT, c = t - i*COUT;
  int r = rank[i];
  const float* br = base + (size_t)i*32;
  const float* hr = h + (size_t)(r >= 0 ? r : 0)*32;
  float s = 0.f;
  #pragma unroll
  for(int d = 0; d < 32; ++d){
    float z = br[d] + ((r >= 0) ? hr[d] : 0.f);
    s += z * W[d*COUT + c];
  }
  out[t] = dinv[i] * s;
}

// y[i][c] = dinv[i]*( sum_{e:dst=i} xwd[src][c] + 2*xwd[i][c] ) + b[c]
template<int C, bool RELU>
__global__ void k_csr_gcn(const int* __restrict__ rowptr, const int* __restrict__ colidx,
                          const float* __restrict__ xwd, const float* __restrict__ dinv,
                          const float* __restrict__ bias, float* __restrict__ out, int n){
  int t = blockIdx.x*blockDim.x + threadIdx.x;
  if(t >= n*C) return;
  int i = t / C, c = t % C;
  float acc = 2.0f * xwd[i*C + c];
  int b = rowptr[i], e = rowptr[i+1];
  for(int p = b; p < e; ++p) acc += xwd[colidx[p]*C + c];
  float y = dinv[i]*acc + bias[c];
  out[t] = RELU ? fmaxf(y, 0.f) : y;
}

// fused: score (tanh(h·p/|p|)) -> bitonic full sort -> perm/rank -> pooled h_out
// single block, 1024 threads, dynamic LDS = MM*8 bytes (MM = pow2 >= n)
template<int MM>
__global__ void k_pool_fused(const float* __restrict__ h, const float* __restrict__ pvec,
                             int n, int k, int* __restrict__ perm, int* __restrict__ rank,
                             float* __restrict__ hout){
  extern __shared__ unsigned long long key[];
  int tid = threadIdx.x;
  float pv[32]; float nrm = 0.f;
  #pragma unroll
  for(int c = 0; c < 32; ++c){ pv[c] = pvec[c]; nrm += pv[c]*pv[c]; }
  float den = sqrtf(nrm);
  for(int i = tid; i < n; i += blockDim.x) rank[i] = -1;
  for(int i = tid; i < MM; i += blockDim.x){
    unsigned long long kk = 0ull;
    if(i < n){
      const float* hr = h + (size_t)i*32;
      float s = 0.f;
      #pragma unroll
      for(int c = 0; c < 32; ++c) s += hr[c]*pv[c];
      float sc = tanhf(s / den);
      unsigned u = __float_as_uint(sc);
      u ^= (u & 0x80000000u) ? 0xFFFFFFFFu : 0x80000000u;   // order-preserving map
      kk = ((unsigned long long)u << 32) | (unsigned)(~(unsigned)i);
    }
    key[i] = kk;
  }
  for(int sz = 2; sz <= MM; sz <<= 1){
    for(int st = sz >> 1; st > 0; st >>= 1){
      __syncthreads();
      for(int i = tid; i < MM; i += blockDim.x){
        int j = i ^ st;
        if(j > i){
          unsigned long long a = key[i], b = key[j];
          bool up = ((i & sz) == 0);
          if(up ? (a < b) : (a > b)){ key[i] = b; key[j] = a; }
        }
      }
    }
  }
  __syncthreads();
  for(int i = tid; i < k; i += blockDim.x){
    int idx = (int)(~(unsigned)(key[i] & 0xFFFFFFFFull));
    perm[i] = idx; rank[idx] = i;
  }
  for(int t = tid; t < k*32; t += blockDim.x){
    int i = t >> 5, c = t & 31;
    unsigned long long kk = key[i];
    int idx = (int)(~(unsigned)(kk & 0xFFFFFFFFull));
    unsigned u = (unsigned)(kk >> 32);
    u = (u & 0x80000000u) ? (u ^ 0x80000000u) : ~u;
    hout[t] = h[(size_t)idx*32 + c] * __uint_as_float(u);
  }
}

// C1[rank[d], rank[j]] += A^2 + 2A via 2-path enumeration (exact integer adds)
__global__ void k_twohop0(const int* __restrict__ ei, int E, const int* __restrict__ rowptr,
                          const int* __restrict__ colidx, const int* __restrict__ rank,
                          float* __restrict__ C, int K){
  int e = blockIdx.x*blockDim.x + threadIdx.x;
  if(e >= E) return;
  int d = ei[E + e];
  int rd = rank[d];
  if(rd < 0) return;
  int s = ei[e];
  float* Crow = C + (size_t)rd * K;
  int rs = rank[s];
  if(rs >= 0) atomicAdd(&Crow[rs], 2.0f);            // 2A term
  for(int p = rowptr[s], pe = rowptr[s+1]; p < pe; ++p){
    int r2 = rank[colidx[p]];
    if(r2 >= 0) atomicAdd(&Crow[r2], 1.0f);          // A^2 term
  }
}

__global__ void k_zerodiag(float* __restrict__ C, int K){
  int i = blockIdx.x*blockDim.x + threadIdx.x;
  if(i < K) C[(size_t)i*K + i] = 0.f;
}

// per-row: nnz count (+1 diag slot), dinv = rsqrt(rowsum+2), fill=0
__global__ void k_row_stat(const float* __restrict__ C, int n, int* __restrict__ cnt,
                           float* __restrict__ dinv, int* __restrict__ fill){
  int i = blockIdx.x;
  const float* row = C + (size_t)i*n;
  int c = 0; float s = 0.f;
  for(int j = threadIdx.x; j < n; j += blockDim.x){ float v = row[j]; if(v != 0.f){ ++c; s += v; } }
  for(int o = 32; o > 0; o >>= 1){ c += __shfl_down(c, o, 64); s += __shfl_down(s, o, 64); }
  __shared__ int shc[4]; __shared__ float shs[4];
  int lane = threadIdx.x & 63, w = threadIdx.x >> 6;
  if(lane == 0){ shc[w] = c; shs[w] = s; }
  __syncthreads();
  if(threadIdx.x == 0){
    int ct = 0; float st = 0.f;
    for(int q = 0; q < (int)(blockDim.x >> 6); ++q){ ct += shc[q]; st += shs[q]; }
    cnt[i] = ct + 1;                 // +1 for the B1 = C1+I diagonal entry
    dinv[i] = rsqrtf(st + 2.0f);
    fill[i] = 0;
  }
}

__global__ void k_csr1_fill(const float* __restrict__ C, int n, const int* __restrict__ rp,
                            int* __restrict__ fill, int* __restrict__ col, float* __restrict__ val){
  int t = blockIdx.x*blockDim.x + threadIdx.x;
  if(t >= n*n) return;
  int i = t / n, j = t - i*n;
  float v = C[t];
  if(v != 0.f){ int p = rp[i] + atomicAdd(&fill[i], 1); col[p] = j; val[p] = v; }
}

__global__ void k_csr1_diag(int n, const int* __restrict__ rp, int* __restrict__ fill,
                            int* __restrict__ col, float* __restrict__ val){
  int i = blockIdx.x*blockDim.x + threadIdx.x;
  if(i >= n) return;
  int p = rp[i] + atomicAdd(&fill[i], 1);
  col[p] = i; val[p] = 1.f;
}

// SpMM GCN over B1-CSR: y = dinv[i]*( hwd[i] + sum_p val*hwd[col] ) + b   (Ah = B1 + I)
template<bool RELU>
__global__ void k_spmm_gcn(const int* __restrict__ rp, const int* __restrict__ ci,
                           const float* __restrict__ cv, const float* __restrict__ hwd,
                           const float* __restrict__ dinv, const float* __restrict__ bias,
                           float* __restrict__ out, int n){
  int t = blockIdx.x*blockDim.x + threadIdx.x;
  if(t >= n*32) return;
  int i = t >> 5, c = t & 31;
  float acc = hwd[i*32 + c];
  for(int p = rp[i], e = rp[i+1]; p < e; ++p) acc += cv[p]*hwd[ci[p]*32 + c];
  float y = dinv[i]*acc + bias[c];
  out[t] = RELU ? fmaxf(y, 0.f) : y;
}

// C2 = B1^2 [perm2][:,perm2], diag<-0, via sparse path enumeration, LDS row accumulator
__global__ void k_twohop_sp(const int* __restrict__ rp, const int* __restrict__ ci,
                            const float* __restrict__ cv, const int* __restrict__ perm2,
                            const int* __restrict__ rank2, float* __restrict__ C2, int K2){
  __shared__ float acc[256];
  int i = blockIdx.x;
  for(int j = threadIdx.x; j < K2; j += blockDim.x) acc[j] = 0.f;
  __syncthreads();
  int qi = perm2[i];
  int b = rp[qi], len = rp[qi+1] - b;
  for(int w = threadIdx.x; w < len*8; w += blockDim.x){
    int p = b + (w >> 3), sub = w & 7;
    int t = ci[p]; float v = cv[p];
    for(int q = rp[t] + sub, qe = rp[t+1]; q < qe; q += 8){
      int j = rank2[ci[q]];
      if(j >= 0) atomicAdd(&acc[j], v*cv[q]);   // exact integer adds
    }
  }
  __syncthreads();
  for(int j = threadIdx.x; j < K2; j += blockDim.x)
    C2[(size_t)i*K2 + j] = (j == i) ? 0.f : acc[j];
}

__global__ void k_rowsum_dinv(const float* __restrict__ C, int n, float* __restrict__ dinv){
  int i = blockIdx.x;
  float s = 0.f;
  for(int j = threadIdx.x; j < n; j += blockDim.x) s += C[(size_t)i*n + j];
  for(int o = 32; o > 0; o >>= 1) s += __shfl_down(s, o, 64);
  __shared__ float sh[4];
  int lane = threadIdx.x & 63, w = threadIdx.x >> 6;
  if(lane == 0) sh[w] = s;
  __syncthreads();
  if(threadIdx.x == 0){
    float t = 0.f;
    for(int q = 0; q < (int)(blockDim.x >> 6); ++q) t += sh[q];
    dinv[i] = rsqrtf(t + 2.0f);
  }
}

// dense GCN, block-per-row, 8-way K-split + LDS reduce
template<bool RELU>
__global__ void k_dgcn_row(const float* __restrict__ C, const float* __restrict__ hwd,
                           const float* __restrict__ dinv, const float* __restrict__ bias,
                           float* __restrict__ out, int n){
  __shared__ float sh[8][32];
  int i = blockIdx.x;
  int c = threadIdx.x & 31, s = threadIdx.x >> 5;
  const float* row = C + (size_t)i*n;
  float acc = 0.f;
  for(int t = s; t < n; t += 8) acc += row[t]*hwd[t*32 + c];
  sh[s][c] = acc;
  __syncthreads();
  if(s == 0){
    float a = sh[0][c]+sh[1][c]+sh[2][c]+sh[3][c]+sh[4][c]+sh[5][c]+sh[6][c]+sh[7][c];
    a += 2.f*hwd[i*32 + c];
    float y = dinv[i]*a + bias[c];
    out[i*32 + c] = RELU ? fmaxf(y, 0.f) : y;
  }
}

// Bp[t][j] = C[t][perm[j]] + (t==perm[j])
__global__ void k_gather_cols(const float* __restrict__ C, int n, const int* __restrict__ perm,
                              int k, float* __restrict__ Bp){
  int t = blockIdx.x*blockDim.x + threadIdx.x;
  if(t >= n*k) return;
  int tt = t / k, j = t % k;
  int qj = perm[j];
  Bp[t] = C[(size_t)tt*n + qj] + ((tt == qj) ? 1.f : 0.f);
}

// out[i][j] = sum_t (C[qi][t]+(t==qi)) * Bp[t][j], diag forced 0
__global__ void k_twohop_dense(const float* __restrict__ C, int n, const int* __restrict__ perm,
                               int k, const float* __restrict__ Bp, float* __restrict__ out){
  int t = blockIdx.x*blockDim.x + threadIdx.x;
  if(t >= k*k) return;
  int i = t / k, j = t % k;
  int qi = perm[i];
  const float* ri = C + (size_t)qi*n;
  float s = 0.f;
  for(int tt = 0; tt < n; ++tt){
    float a = ri[tt] + ((tt == qi) ? 1.f : 0.f);
    s += a * Bp[(size_t)tt*k + j];
  }
  out[t] = (i == j) ? 0.f : s;
}

__global__ void k_bn(float* __restrict__ out, int n, const float* __restrict__ g,
                     const float* __restrict__ b){
  __shared__ float sh[16];
  __shared__ float sval;
  int tid = threadIdx.x, lane = tid & 63, w = tid >> 6;
  int nw = blockDim.x >> 6;
  float s = 0.f;
  for(int i = tid; i < n; i += blockDim.x) s += out[i*4];
  for(int o = 32; o > 0; o >>= 1) s += __shfl_down(s, o, 64);
  if(lane == 0) sh[w] = s;
  __syncthreads();
  if(tid == 0){ float t = 0.f; for(int q = 0; q < nw; ++q) t += sh[q]; sval = t / n; }
  __syncthreads();
  float mean = sval;
  float v = 0.f;
  for(int i = tid; i < n; i += blockDim.x){ float d = out[i*4] - mean; v += d*d; }
  for(int o = 32; o > 0; o >>= 1) v += __shfl_down(v, o, 64);
  __syncthreads();
  if(lane == 0) sh[w] = v;
  __syncthreads();
  if(tid == 0){ float t = 0.f; for(int q = 0; q < nw; ++q) t += sh[q]; sval = t / n; }
  __syncthreads();
  float var = sval;
  float scale = g[0] * rsqrtf(var + 1e-5f);
  float beta = b[0];
  for(int i = tid; i < n; i += blockDim.x){
    float r = scale*(out[i*4] - mean) + beta;
    out[i*4] = 1.f / (1.f + expf(-r));
  }
}

extern "C" void kernel_launch(void* const* d_in, const int* in_sizes, int n_in,
                              void* d_out, int out_size, void* d_ws, size_t ws_size,
                              hipStream_t stream){
  const float* x  =(const float*)d_in[0];
  const int*   ei =(const int*)  d_in[1];
  const float* W0 =(const float*)d_in[2];  const float* b0 =(const float*)d_in[3];
  const float* W1 =(const float*)d_in[4];  const float* b1 =(const float*)d_in[5];
  const float* W2 =(const float*)d_in[6];  const float* b2 =(const float*)d_in[7];
  const float* W3 =(const float*)d_in[8];  const float* b3 =(const float*)d_in[9];
  const float* p0 =(const float*)d_in[10];
  const float* p1 =(const float*)d_in[11];
  const float* p2 =(const float*)d_in[12];
  const float* Wu0=(const float*)d_in[13]; const float* bu0=(const float*)d_in[14];
  const float* Wu1=(const float*)d_in[15]; const float* bu1=(const float*)d_in[16];
  const float* Wu2=(const float*)d_in[17]; const float* bu2=(const float*)d_in[18];
  const float* bng=(const float*)d_in[19]; const float* bnb=(const float*)d_in[20];
  float* out = (float*)d_out;

  const int n0 = in_sizes[0] / 3;       // 6000
  const int E  = in_sizes[1] / 2;       // 96000
  const int K1 = (n0 + 4) / 5;          // 1200
  const int K2 = (K1 + 4) / 5;          // 240
  const int K3 = (K2 + 4) / 5;          // 48
  const int CAP1 = 384*1024;            // B1-CSR capacity (expected nnz ~69K, 5.5x margin)

  char* wsp = (char*)d_ws; size_t off = 0;
  auto alloc = [&](size_t bytes)->char*{
    char* p = wsp + off; off = (off + bytes + 255) & ~((size_t)255); return p;
  };

  int*   cnt    = (int*)  alloc((size_t)n0*4);          // reused: level-1 row counts
  int*   rowptr = (int*)  alloc((size_t)(n0+1)*4);
  int*   fill   = (int*)  alloc((size_t)n0*4);          // reused: level-1 fill
  int*   colidx = (int*)  alloc((size_t)E*4);
  float* dinv0  = (float*)alloc((size_t)n0*4);
  float* hwd    = (float*)alloc((size_t)n0*32*4);       // xwd0 + all later (z·W) temps
  float* h0     = (float*)alloc((size_t)n0*32*4);
  int*   perm1  = (int*)  alloc((size_t)K1*4);
  int*   rank1  = (int*)  alloc((size_t)n0*4);
  float* h1p    = (float*)alloc((size_t)K1*32*4);
  float* C1     = (float*)alloc((size_t)K1*K1*4);
  float* dinv1  = (float*)alloc((size_t)K1*4);
  int*   rowptr1= (int*)  alloc((size_t)(K1+1)*4);
  int*   col1   = (int*)  alloc((size_t)CAP1*4);
  float* val1   = (float*)alloc((size_t)CAP1*4);
  float* h1     = (float*)alloc((size_t)K1*32*4);
  int*   perm2  = (int*)  alloc((size_t)K2*4);
  int*   rank2  = (int*)  alloc((size_t)K1*4);
  float* h2p    = (float*)alloc((size_t)K2*32*4);
  float* C2     = (float*)alloc((size_t)K2*K2*4);
  float* dinv2  = (float*)alloc((size_t)K2*4);
  float* h2     = (float*)alloc((size_t)K2*32*4);
  int*   perm3  = (int*)  alloc((size_t)K3*4);
  int*   rank3  = (int*)  alloc((size_t)K2*4);
  float* h3p    = (float*)alloc((size_t)K3*32*4);
  float* C3     = (float*)alloc((size_t)K3*K3*4);
  float* dinv3  = (float*)alloc((size_t)K3*4);
  float* h3     = (float*)alloc((size_t)K3*32*4);
  float* Bp     = (float*)alloc((size_t)K2*K3*4);
  float* hu2    = (float*)alloc((size_t)K2*32*4);
  float* hu1    = (float*)alloc((size_t)K1*32*4);

  hipMemsetAsync(cnt,  0, (size_t)n0*4,    stream);
  hipMemsetAsync(fill, 0, (size_t)n0*4,    stream);
  hipMemsetAsync(C1,   0, (size_t)K1*K1*4, stream);

  const int gE = (E + TPB - 1) / TPB;
  // ---- CSR0 + deg ----
  k_count  <<<gE, TPB, 0, stream>>>(ei, E, cnt);
  k_scan<6><<<1, 1024, 0, stream>>>(cnt, n0, rowptr);
  k_fill   <<<gE, TPB, 0, stream>>>(ei, E, rowptr, fill, colidx);
  k_dinv   <<<(n0+TPB-1)/TPB, TPB, 0, stream>>>(cnt, n0, dinv0);
  // ---- GCN0 (n0, 3->32, relu) ----
  k_mm_dinv<<<(n0*32+TPB-1)/TPB, TPB, 0, stream>>>(x, W0, dinv0, hwd, n0, 3, 32);
  k_csr_gcn<32,true><<<(n0*32+TPB-1)/TPB, TPB, 0, stream>>>(rowptr, colidx, hwd, dinv0, b0, h0, n0);
  // ---- pool 1 (fused score+sort+rank+pool) ----
  k_pool_fused<8192><<<1, 1024, 8192*8, stream>>>(h0, p0, n0, K1, perm1, rank1, h1p);
  // ---- two-hop level0 -> C1 (sparse path enumeration) ----
  k_twohop0 <<<gE, TPB, 0, stream>>>(ei, E, rowptr, colidx, rank1, C1, K1);
  k_zerodiag<<<(K1+TPB-1)/TPB, TPB, 0, stream>>>(C1, K1);
  // ---- B1 = C1+I CSR build ----
  k_row_stat <<<K1, 256, 0, stream>>>(C1, K1, cnt, dinv1, fill);
  k_scan<2>  <<<1, 1024, 0, stream>>>(cnt, K1, rowptr1);
  k_csr1_fill<<<(K1*K1+TPB-1)/TPB, TPB, 0, stream>>>(C1, K1, rowptr1, fill, col1, val1);
  k_csr1_diag<<<(K1+TPB-1)/TPB, TPB, 0, stream>>>(K1, rowptr1, fill, col1, val1);
  // ---- GCN1 (K1, sparse, relu) ----
  k_mm_dinv<<<(K1*32+TPB-1)/TPB, TPB, 0, stream>>>(h1p, W1, dinv1, hwd, K1, 32, 32);
  k_spmm_gcn<true><<<(K1*32+TPB-1)/TPB, TPB, 0, stream>>>(rowptr1, col1, val1, hwd, dinv1, b1, h1, K1);
  // ---- pool 2 ----
  k_pool_fused<2048><<<1, 1024, 2048*8, stream>>>(h1, p1, K1, K2, perm2, rank2, h2p);
  // ---- two-hop level1 -> C2 (sparse) ----
  k_twohop_sp<<<K2, 256, 0, stream>>>(rowptr1, col1, val1, perm2, rank2, C2, K2);
  // ---- GCN2 (K2, dense row-block, relu) ----
  k_rowsum_dinv<<<K2, 256, 0, stream>>>(C2, K2, dinv2);
  k_mm_dinv<<<(K2*32+TPB-1)/TPB, TPB, 0, stream>>>(h2p, W2, dinv2, hwd, K2, 32, 32);
  k_dgcn_row<true><<<K2, 256, 0, stream>>>(C2, hwd, dinv2, b2, h2, K2);
  // ---- pool 3 ----
  k_pool_fused<256><<<1, 1024, 256*8, stream>>>(h2, p2, K2, K3, perm3, rank3, h3p);
  // ---- two-hop level2 -> C3 ----
  k_gather_cols <<<(K2*K3+TPB-1)/TPB, TPB, 0, stream>>>(C2, K2, perm3, K3, Bp);
  k_twohop_dense<<<(K3*K3+TPB-1)/TPB, TPB, 0, stream>>>(C2, K2, perm3, K3, Bp, C3);
  // ---- GCN3 (K3, relu) ----
  k_rowsum_dinv<<<K3, 256, 0, stream>>>(C3, K3, dinv3);
  k_mm_dinv<<<(K3*32+TPB-1)/TPB, TPB, 0, stream>>>(h3p, W3, dinv3, hwd, K3, 32, 32);
  k_dgcn_row<true><<<K3, 256, 0, stream>>>(C3, hwd, dinv3, b3, h3, K3);
  // ---- up 0 (level 2, relu) ----
  k_addup_mm<32><<<(K2*32+TPB-1)/TPB, TPB, 0, stream>>>(h2, h3, rank3, Wu0, dinv2, hwd, K2);
  k_dgcn_row<true><<<K2, 256, 0, stream>>>(C2, hwd, dinv2, bu0, hu2, K2);
  // ---- up 1 (level 1, sparse, relu) ----
  k_addup_mm<32><<<(K1*32+TPB-1)/TPB, TPB, 0, stream>>>(h1, hu2, rank2, Wu1, dinv1, hwd, K1);
  k_spmm_gcn<true><<<(K1*32+TPB-1)/TPB, TPB, 0, stream>>>(rowptr1, col1, val1, hwd, dinv1, bu1, hu1, K1);
  // ---- up 2 (level 0, 32->4, no relu) ----
  k_addup_mm<4><<<(n0*4+TPB-1)/TPB, TPB, 0, stream>>>(h0, hu1, rank1, Wu2, dinv0, hwd, n0);
  k_csr_gcn<4,false><<<(n0*4+TPB-1)/TPB, TPB, 0, stream>>>(rowptr, colidx, hwd, dinv0, bu2, out, n0);
  // ---- final BN + sigmoid on column 0 ----
  k_bn<<<1, 1024, 0, stream>>>(out, n0, bng, bnb);
}

// Round 3
// 289.163 us; speedup vs baseline: 3.8908x; 1.8010x over previous
//
#include <hip/hip_runtime.h>
#include <hip/hip_bf16.h>

#define TPB 256

// ---------------- CSR build (level 0 adjacency) ----------------
__global__ void k_count(const int* __restrict__ ei, int E, int* __restrict__ cnt){
  int e = blockIdx.x*blockDim.x + threadIdx.x;
  if(e < E) atomicAdd(&cnt[ei[E + e]], 1);   // rows = dst = edge_index[1]
}

// single-block scan, IPT elements per thread (1024 threads)
template<int IPT>
__global__ void k_scan(const int* __restrict__ cnt, int n, int* __restrict__ rowptr){
  int tid = threadIdx.x;
  int base = tid * IPT;
  int loc[IPT]; int s = 0;
  #pragma unroll
  for(int q = 0; q < IPT; ++q){ int i = base + q; int v = (i < n) ? cnt[i] : 0; s += v; loc[q] = s; }
  int lane = tid & 63, w = tid >> 6;
  int ss = s;
  #pragma unroll
  for(int o = 1; o < 64; o <<= 1){ int t = __shfl_up(ss, o, 64); if(lane >= o) ss += t; }
  __shared__ int wsum[16];
  if(lane == 63) wsum[w] = ss;
  __syncthreads();
  if(tid < 16){
    int t = wsum[tid];
    for(int o = 1; o < 16; o <<= 1){ int u = __shfl_up(t, o, 64); if(tid >= o) t += u; }
    wsum[tid] = t;
  }
  __syncthreads();
  int excl = ss - s + (w > 0 ? wsum[w-1] : 0);
  if(tid == 0) rowptr[0] = 0;
  #pragma unroll
  for(int q = 0; q < IPT; ++q){ int i = base + q; if(i < n) rowptr[i+1] = excl + loc[q]; }
}

__global__ void k_fill(const int* __restrict__ ei, int E, const int* __restrict__ rowptr,
                       int* __restrict__ fill, int* __restrict__ colidx){
  int e = blockIdx.x*blockDim.x + threadIdx.x;
  if(e >= E) return;
  int d = ei[E + e], s = ei[e];
  int p = rowptr[d] + atomicAdd(&fill[d], 1);
  colidx[p] = s;
}

__global__ void k_dinv(const int* __restrict__ cnt, int n, float* __restrict__ dinv){
  int i = blockIdx.x*blockDim.x + threadIdx.x;
  if(i < n) dinv[i] = rsqrtf((float)cnt[i] + 2.0f);   // deg = rowsum(A)+2
}

// out[i][c] = dinv[i] * sum_d h[i][d]*W[d][c]
__global__ void k_mm_dinv(const float* __restrict__ h, const float* __restrict__ W,
                          const float* __restrict__ dinv, float* __restrict__ out,
                          int n, int cin, int cout){
  int t = blockIdx.x*blockDim.x + threadIdx.x;
  if(t >= n*cout) return;
  int i = t / cout, c = t % cout;
  float s = 0.f;
  for(int d = 0; d < cin; ++d) s += h[i*cin + d] * W[d*cout + c];
  out[t] = dinv[i] * s;
}

// fused unpool-add + weight GEMM: out = dinv[i] * ((base + scatter(h))·W)
template<int COUT>
__global__ void k_addup_mm(const float* __restrict__ base, const float* __restrict__ h,
                           const int* __restrict__ rank, const float* __restrict__ W,
                           const float* __restrict__ dinv, float* __restrict__ out, int n){
  int t = blockIdx.x*blockDim.x + threadIdx.x;
  if(t >= n*COUT) return;
  int i = t / COUT, c = t - i*COUT;
  int r = rank[i];
  const float* br = base + (size_t)i*32;
  const float* hr = h + (size_t)(r >= 0 ? r : 0)*32;
  float s = 0.f;
  #pragma unroll
  for(int d = 0; d < 32; ++d){
    float z = br[d] + ((r >= 0) ? hr[d] : 0.f);
    s += z * W[d*COUT + c];
  }
  out[t] = dinv[i] * s;
}

// y[i][c] = dinv[i]*( sum_{e:dst=i} xwd[src][c] + 2*xwd[i][c] ) + b[c]
template<int C, bool RELU>
__global__ void k_csr_gcn(const int* __restrict__ rowptr, const int* __restrict__ colidx,
                          const float* __restrict__ xwd, const float* __restrict__ dinv,
                          const float* __restrict__ bias, float* __restrict__ out, int n){
  int t = blockIdx.x*blockDim.x + threadIdx.x;
  if(t >= n*C) return;
  int i = t / C, c = t % C;
  float acc = 2.0f * xwd[i*C + c];
  int b = rowptr[i], e = rowptr[i+1];
  for(int p = b; p < e; ++p) acc += xwd[colidx[p]*C + c];
  float y = dinv[i]*acc + bias[c];
  out[t] = RELU ? fmaxf(y, 0.f) : y;
}

// fused: score -> exact top-k via MSD radix-select on unique 64-bit keys ->
// deterministic ascending-index compaction -> perm/rank/pooled h_out.
// Selected SET identical to jax.lax.top_k (keys unique; ties prefer lower idx).
template<int NMAX>
__global__ __launch_bounds__(1024)
void k_pool_radix(const float* __restrict__ h, const float* __restrict__ pvec,
                  int n, int k, int* __restrict__ perm, int* __restrict__ rank,
                  float* __restrict__ hout){
  __shared__ unsigned long long keys[NMAX];
  __shared__ int bins[2048];
  __shared__ int wsum[16];
  __shared__ unsigned long long s_prefix;
  __shared__ int s_rk, s_found, s_cntgt;
  int tid = threadIdx.x, lane = tid & 63, w = tid >> 6;

  float pv[32]; float nrm = 0.f;
  #pragma unroll
  for(int c = 0; c < 32; ++c){ pv[c] = pvec[c]; nrm += pv[c]*pv[c]; }
  float den = sqrtf(nrm);

  for(int i = tid; i < n; i += 1024) rank[i] = -1;
  for(int i = tid; i < n; i += 1024){
    const float* hr = h + (size_t)i*32;
    float s = 0.f;
    #pragma unroll
    for(int c = 0; c < 32; ++c) s += hr[c]*pv[c];
    float sc = tanhf(s/den);
    unsigned u = __float_as_uint(sc);
    u ^= (u & 0x80000000u) ? 0xFFFFFFFFu : 0x80000000u;   // order-preserving map
    keys[i] = ((unsigned long long)u << 32) | (unsigned)(~(unsigned)i);
  }
  if(tid == 0){ s_prefix = 0ull; s_rk = k; }
  __syncthreads();

  // 6 MSD passes: widths 11,11,11,11,11,9 cover all 64 bits
  for(int pass = 0; pass < 6; ++pass){
    const int width = (pass < 5) ? 11 : 9;
    const int shift = (pass < 5) ? (53 - 11*pass) : 0;
    const int nb = 1 << width;
    for(int b2 = tid; b2 < nb; b2 += 1024) bins[b2] = 0;
    __syncthreads();
    unsigned long long prefix = s_prefix;
    int rk = s_rk;
    const int hs = shift + width;            // ==64 on pass 0 (guarded below)
    for(int i = tid; i < n; i += 1024){
      unsigned long long kk = keys[i];
      bool match = (pass == 0) || ((kk >> hs) == (prefix >> hs));
      if(match) atomicAdd(&bins[(int)((kk >> shift) & (unsigned long long)(nb-1))], 1);
    }
    __syncthreads();
    // inclusive suffix sums: bins[b] <- count of matching elems with digit >= b
    int ipt = (nb + 1023) >> 10;   // 2 or 1
    int loc0 = 0, loc1 = 0, s = 0;
    { int r = tid*ipt; int v = (r < nb) ? bins[nb-1-r] : 0; s += v; loc0 = s;
      if(ipt == 2){ int r2 = r+1; int v2 = (r2 < nb) ? bins[nb-1-r2] : 0; s += v2; loc1 = s; } }
    int ss = s;
    #pragma unroll
    for(int o = 1; o < 64; o <<= 1){ int t2 = __shfl_up(ss, o, 64); if(lane >= o) ss += t2; }
    if(lane == 63) wsum[w] = ss;
    __syncthreads();
    if(tid < 16){
      int t2 = wsum[tid];
      #pragma unroll
      for(int o = 1; o < 16; o <<= 1){ int u2 = __shfl_up(t2, o, 64); if(tid >= o) t2 += u2; }
      wsum[tid] = t2;
    }
    __syncthreads();
    int excl = ss - s + (w ? wsum[w-1] : 0);
    { int r = tid*ipt; if(r < nb) bins[nb-1-r] = excl + loc0;
      if(ipt == 2){ int r2 = r+1; if(r2 < nb) bins[nb-1-r2] = excl + loc1; } }
    __syncthreads();
    for(int b2 = tid; b2 < nb; b2 += 1024){
      int cge = bins[b2];
      int cgt = (b2+1 < nb) ? bins[b2+1] : 0;
      if(cge >= rk && cgt < rk){ s_found = b2; s_cntgt = cgt; }  // unique b2
    }
    __syncthreads();
    if(tid == 0){ s_prefix |= ((unsigned long long)s_found) << shift; s_rk -= s_cntgt; }
    __syncthreads();
  }
  unsigned long long T = s_prefix;   // exact k-th largest key

  // ordered compaction (ascending original index), exactly k survivors
  int CH = (n + 1023) >> 10;
  int base = tid*CH, cnt = 0;
  for(int q = 0; q < CH; ++q){ int i = base+q; if(i < n && keys[i] >= T) ++cnt; }
  int ss2 = cnt;
  #pragma unroll
  for(int o = 1; o < 64; o <<= 1){ int t2 = __shfl_up(ss2, o, 64); if(lane >= o) ss2 += t2; }
  if(lane == 63) wsum[w] = ss2;
  __syncthreads();
  if(tid < 16){
    int t2 = wsum[tid];
    #pragma unroll
    for(int o = 1; o < 16; o <<= 1){ int u2 = __shfl_up(t2, o, 64); if(tid >= o) t2 += u2; }
    wsum[tid] = t2;
  }
  __syncthreads();
  int pos = ss2 - cnt + (w ? wsum[w-1] : 0);
  for(int q = 0; q < CH; ++q){
    int i = base+q;
    if(i < n && keys[i] >= T){ perm[pos] = i; rank[i] = pos; ++pos; }
  }
  __syncthreads();
  for(int t = tid; t < k*32; t += 1024){
    int i = t >> 5, c = t & 31;
    int idx = perm[i];
    unsigned u = (unsigned)(keys[idx] >> 32);
    u = (u & 0x80000000u) ? (u ^ 0x80000000u) : ~u;    // unmap -> score
    hout[t] = h[(size_t)idx*32 + c] * __uint_as_float(u);
  }
}

// Build B1 = twohop0(A)[perm,perm] + I directly as CSR (block per pooled row, LDS row).
// Also emits dinv1 = rsqrt(rowsum(C1)+2). Row bases via atomic cursor (contents per
// row deterministic -> downstream output deterministic).
__global__ __launch_bounds__(256)
void k_build_B1(const int* __restrict__ rowptr, const int* __restrict__ colidx,
                const int* __restrict__ perm1, const int* __restrict__ rank1, int K1,
                float* __restrict__ dinv1, int* __restrict__ rowbeg, int* __restrict__ rowend,
                int* __restrict__ col1, float* __restrict__ val1, int* __restrict__ cursor){
  __shared__ float row[1216];
  __shared__ int wsum[4];
  __shared__ float fs[4];
  __shared__ int s_base;
  int tid = threadIdx.x, lane = tid & 63, w = tid >> 6;
  int i = blockIdx.x;
  for(int j = tid; j < K1; j += 256) row[j] = 0.f;
  __syncthreads();
  int d = perm1[i];
  int b = rowptr[d], len = rowptr[d+1]-b;
  for(int p = tid; p < len; p += 256){
    int s = colidx[b+p]; int rs = rank1[s];
    if(rs >= 0) atomicAdd(&row[rs], 2.0f);          // 2A term
  }
  for(int ww = tid; ww < len*8; ww += 256){
    int p = ww >> 3, sub = ww & 7;
    int s = colidx[b+p];
    for(int q = rowptr[s]+sub, qe = rowptr[s+1]; q < qe; q += 8){
      int r2 = rank1[colidx[q]];
      if(r2 >= 0) atomicAdd(&row[r2], 1.0f);        // A^2 (2-path) term
    }
  }
  __syncthreads();
  if(tid == 0) row[i] = 0.f;                        // diag <- 0
  __syncthreads();
  float s = 0.f;
  for(int j = tid; j < K1; j += 256) s += row[j];
  for(int o = 32; o > 0; o >>= 1) s += __shfl_down(s, o, 64);
  if(lane == 0) fs[w] = s;
  __syncthreads();
  if(tid == 0){
    dinv1[i] = rsqrtf(fs[0]+fs[1]+fs[2]+fs[3] + 2.0f);
    row[i] = 1.0f;                                  // +I for B1
  }
  __syncthreads();
  int CH = (K1 + 255) >> 8;
  int base = tid*CH, cnt = 0;
  for(int q = 0; q < CH; ++q){ int j = base+q; if(j < K1 && row[j] != 0.f) ++cnt; }
  int ss = cnt;
  #pragma unroll
  for(int o = 1; o < 64; o <<= 1){ int t2 = __shfl_up(ss, o, 64); if(lane >= o) ss += t2; }
  if(lane == 63) wsum[w] = ss;
  __syncthreads();
  if(tid < 4){
    int t2 = wsum[tid];
    for(int o = 1; o < 4; o <<= 1){ int u2 = __shfl_up(t2, o, 64); if(tid >= o) t2 += u2; }
    wsum[tid] = t2;
  }
  __syncthreads();
  if(tid == 0) s_base = atomicAdd(cursor, wsum[3]);
  __syncthreads();
  int off = s_base + ss - cnt + (w ? wsum[w-1] : 0);
  for(int q = 0; q < CH; ++q){
    int j = base+q;
    if(j < K1 && row[j] != 0.f){ col1[off] = j; val1[off] = row[j]; ++off; }
  }
  if(tid == 0){ rowbeg[i] = s_base; rowend[i] = s_base + wsum[3]; }
}

// SpMM GCN over B1-CSR: y = dinv[i]*( hwd[i] + sum_p val*hwd[col] ) + b   (Ah = B1 + I)
template<bool RELU>
__global__ void k_spmm_gcn(const int* __restrict__ rb, const int* __restrict__ re,
                           const int* __restrict__ ci, const float* __restrict__ cv,
                           const float* __restrict__ hwd, const float* __restrict__ dinv,
                           const float* __restrict__ bias, float* __restrict__ out, int n){
  int t = blockIdx.x*blockDim.x + threadIdx.x;
  if(t >= n*32) return;
  int i = t >> 5, c = t & 31;
  float acc = hwd[i*32 + c];
  for(int p = rb[i], e = re[i]; p < e; ++p) acc += cv[p]*hwd[ci[p]*32 + c];
  float y = dinv[i]*acc + bias[c];
  out[t] = RELU ? fmaxf(y, 0.f) : y;
}

// C2 = B1^2 [perm2][:,perm2], diag<-0, via sparse path enumeration; also emits dinv2
__global__ __launch_bounds__(256)
void k_twohop_sp(const int* __restrict__ rb, const int* __restrict__ re,
                 const int* __restrict__ ci, const float* __restrict__ cv,
                 const int* __restrict__ perm2, const int* __restrict__ rank2,
                 float* __restrict__ C2, float* __restrict__ dinv2, int K2){
  __shared__ float acc[256];
  __shared__ float fs[4];
  int i = blockIdx.x, tid = threadIdx.x, lane = tid & 63, w = tid >> 6;
  for(int j = tid; j < K2; j += 256) acc[j] = 0.f;
  __syncthreads();
  int qi = perm2[i];
  int b = rb[qi], len = re[qi]-b;
  for(int ww = tid; ww < len*8; ww += 256){
    int p = b + (ww >> 3), sub = ww & 7;
    int t = ci[p]; float v = cv[p];
    for(int q = rb[t] + sub, qe = re[t]; q < qe; q += 8){
      int j = rank2[ci[q]];
      if(j >= 0) atomicAdd(&acc[j], v*cv[q]);   // exact integer adds
    }
  }
  __syncthreads();
  if(tid == 0) acc[i] = 0.f;
  __syncthreads();
  float s = 0.f;
  for(int j = tid; j < K2; j += 256) s += acc[j];
  for(int o = 32; o > 0; o >>= 1) s += __shfl_down(s, o, 64);
  if(lane == 0) fs[w] = s;
  __syncthreads();
  if(tid == 0) dinv2[i] = rsqrtf(fs[0]+fs[1]+fs[2]+fs[3] + 2.0f);
  for(int j = tid; j < K2; j += 256) C2[(size_t)i*K2 + j] = acc[j];
}

// dense GCN, block-per-row, 8-way K-split + LDS reduce
template<bool RELU>
__global__ void k_dgcn_row(const float* __restrict__ C, const float* __restrict__ hwd,
                           const float* __restrict__ dinv, const float* __restrict__ bias,
                           float* __restrict__ out, int n){
  __shared__ float sh[8][32];
  int i = blockIdx.x;
  int c = threadIdx.x & 31, s = threadIdx.x >> 5;
  const float* row = C + (size_t)i*n;
  float acc = 0.f;
  for(int t = s; t < n; t += 8) acc += row[t]*hwd[t*32 + c];
  sh[s][c] = acc;
  __syncthreads();
  if(s == 0){
    float a = sh[0][c]+sh[1][c]+sh[2][c]+sh[3][c]+sh[4][c]+sh[5][c]+sh[6][c]+sh[7][c];
    a += 2.f*hwd[i*32 + c];
    float y = dinv[i]*a + bias[c];
    out[i*32 + c] = RELU ? fmaxf(y, 0.f) : y;
  }
}

// Bp[t][j] = C[t][perm[j]] + (t==perm[j])
__global__ void k_gather_cols(const float* __restrict__ C, int n, const int* __restrict__ perm,
                              int k, float* __restrict__ Bp){
  int t = blockIdx.x*blockDim.x + threadIdx.x;
  if(t >= n*k) return;
  int tt = t / k, j = t % k;
  int qj = perm[j];
  Bp[t] = C[(size_t)tt*n + qj] + ((tt == qj) ? 1.f : 0.f);
}

// level-2 two-hop: block per output row; C3[i][j] = sum_t (C2[qi][t]+(t==qi))*Bp[t][j],
// diag<-0; also emits dinv3
__global__ __launch_bounds__(256)
void k_twohop_d3(const float* __restrict__ C2, int n, const int* __restrict__ perm3,
                 int k, const float* __restrict__ Bp, float* __restrict__ C3,
                 float* __restrict__ dinv3){
  __shared__ float acc[4][64];
  int i = blockIdx.x, tid = threadIdx.x;
  int col = tid & 63, st = tid >> 6;
  int qi = perm3[i];
  float a = 0.f;
  if(col < k){
    for(int tt = st; tt < n; tt += 4){
      float av = C2[(size_t)qi*n + tt] + ((tt == qi) ? 1.f : 0.f);
      a += av * Bp[(size_t)tt*k + col];
    }
  }
  acc[st][col] = a;
  __syncthreads();
  if(st == 0){
    float v = acc[0][col]+acc[1][col]+acc[2][col]+acc[3][col];
    if(col == i) v = 0.f;
    if(col < k) C3[(size_t)i*k + col] = v;
    float sv = (col < k) ? v : 0.f;
    for(int o = 32; o > 0; o >>= 1) sv += __shfl_down(sv, o, 64);
    if(col == 0) dinv3[i] = rsqrtf(sv + 2.0f);
  }
}

__global__ void k_bn(float* __restrict__ out, int n, const float* __restrict__ g,
                     const float* __restrict__ b){
  __shared__ float sh[16];
  __shared__ float sval;
  int tid = threadIdx.x, lane = tid & 63, w = tid >> 6;
  int nw = blockDim.x >> 6;
  float s = 0.f;
  for(int i = tid; i < n; i += blockDim.x) s += out[i*4];
  for(int o = 32; o > 0; o >>= 1) s += __shfl_down(s, o, 64);
  if(lane == 0) sh[w] = s;
  __syncthreads();
  if(tid == 0){ float t = 0.f; for(int q = 0; q < nw; ++q) t += sh[q]; sval = t / n; }
  __syncthreads();
  float mean = sval;
  float v = 0.f;
  for(int i = tid; i < n; i += blockDim.x){ float d = out[i*4] - mean; v += d*d; }
  for(int o = 32; o > 0; o >>= 1) v += __shfl_down(v, o, 64);
  __syncthreads();
  if(lane == 0) sh[w] = v;
  __syncthreads();
  if(tid == 0){ float t = 0.f; for(int q = 0; q < nw; ++q) t += sh[q]; sval = t / n; }
  __syncthreads();
  float var = sval;
  float scale = g[0] * rsqrtf(var + 1e-5f);
  float beta = b[0];
  for(int i = tid; i < n; i += blockDim.x){
    float r = scale*(out[i*4] - mean) + beta;
    out[i*4] = 1.f / (1.f + expf(-r));
  }
}

extern "C" void kernel_launch(void* const* d_in, const int* in_sizes, int n_in,
                              void* d_out, int out_size, void* d_ws, size_t ws_size,
                              hipStream_t stream){
  const float* x  =(const float*)d_in[0];
  const int*   ei =(const int*)  d_in[1];
  const float* W0 =(const float*)d_in[2];  const float* b0 =(const float*)d_in[3];
  const float* W1 =(const float*)d_in[4];  const float* b1 =(const float*)d_in[5];
  const float* W2 =(const float*)d_in[6];  const float* b2 =(const float*)d_in[7];
  const float* W3 =(const float*)d_in[8];  const float* b3 =(const float*)d_in[9];
  const float* p0 =(const float*)d_in[10];
  const float* p1 =(const float*)d_in[11];
  const float* p2 =(const float*)d_in[12];
  const float* Wu0=(const float*)d_in[13]; const float* bu0=(const float*)d_in[14];
  const float* Wu1=(const float*)d_in[15]; const float* bu1=(const float*)d_in[16];
  const float* Wu2=(const float*)d_in[17]; const float* bu2=(const float*)d_in[18];
  const float* bng=(const float*)d_in[19]; const float* bnb=(const float*)d_in[20];
  float* out = (float*)d_out;

  const int n0 = in_sizes[0] / 3;       // 6000
  const int E  = in_sizes[1] / 2;       // 96000
  const int K1 = (n0 + 4) / 5;          // 1200
  const int K2 = (K1 + 4) / 5;          // 240
  const int K3 = (K2 + 4) / 5;          // 48
  const int CAP1 = 512*1024;            // B1-CSR capacity (expected ~70K nnz)

  char* wsp = (char*)d_ws; size_t off = 0;
  auto alloc = [&](size_t bytes)->char*{
    char* p = wsp + off; off = (off + bytes + 255) & ~((size_t)255); return p;
  };

  // zeroed region: cnt | fill | cursor (single memset)
  int*   zreg   = (int*)  alloc((size_t)(2*n0+64)*4);
  int*   cnt    = zreg;
  int*   fill   = zreg + n0;
  int*   cursor = zreg + 2*n0;
  int*   rowptr = (int*)  alloc((size_t)(n0+1)*4);
  int*   colidx = (int*)  alloc((size_t)E*4);
  float* dinv0  = (float*)alloc((size_t)n0*4);
  float* hwd    = (float*)alloc((size_t)n0*32*4);
  float* h0     = (float*)alloc((size_t)n0*32*4);
  int*   perm1  = (int*)  alloc((size_t)K1*4);
  int*   rank1  = (int*)  alloc((size_t)n0*4);
  float* h1p    = (float*)alloc((size_t)K1*32*4);
  float* dinv1  = (float*)alloc((size_t)K1*4);
  int*   rowbeg1= (int*)  alloc((size_t)K1*4);
  int*   rowend1= (int*)  alloc((size_t)K1*4);
  int*   col1   = (int*)  alloc((size_t)CAP1*4);
  float* val1   = (float*)alloc((size_t)CAP1*4);
  float* h1     = (float*)alloc((size_t)K1*32*4);
  int*   perm2  = (int*)  alloc((size_t)K2*4);
  int*   rank2  = (int*)  alloc((size_t)K1*4);
  float* h2p    = (float*)alloc((size_t)K2*32*4);
  float* C2     = (float*)alloc((size_t)K2*K2*4);
  float* dinv2  = (float*)alloc((size_t)K2*4);
  float* h2     = (float*)alloc((size_t)K2*32*4);
  int*   perm3  = (int*)  alloc((size_t)K3*4);
  int*   rank3  = (int*)  alloc((size_t)K2*4);
  float* h3p    = (float*)alloc((size_t)K3*32*4);
  float* C3     = (float*)alloc((size_t)K3*K3*4);
  float* dinv3  = (float*)alloc((size_t)K3*4);
  float* h3     = (float*)alloc((size_t)K3*32*4);
  float* Bp     = (float*)alloc((size_t)K2*K3*4);
  float* hu2    = (float*)alloc((size_t)K2*32*4);
  float* hu1    = (float*)alloc((size_t)K1*32*4);

  hipMemsetAsync(zreg, 0, (size_t)(2*n0+64)*4, stream);

  const int gE = (E + TPB - 1) / TPB;
  // ---- CSR0 + deg ----
  k_count  <<<gE, TPB, 0, stream>>>(ei, E, cnt);
  k_scan<6><<<1, 1024, 0, stream>>>(cnt, n0, rowptr);
  k_fill   <<<gE, TPB, 0, stream>>>(ei, E, rowptr, fill, colidx);
  k_dinv   <<<(n0+TPB-1)/TPB, TPB, 0, stream>>>(cnt, n0, dinv0);
  // ---- GCN0 (n0, 3->32, relu) ----
  k_mm_dinv<<<(n0*32+TPB-1)/TPB, TPB, 0, stream>>>(x, W0, dinv0, hwd, n0, 3, 32);
  k_csr_gcn<32,true><<<(n0*32+TPB-1)/TPB, TPB, 0, stream>>>(rowptr, colidx, hwd, dinv0, b0, h0, n0);
  // ---- pool 1 ----
  k_pool_radix<6144><<<1, 1024, 0, stream>>>(h0, p0, n0, K1, perm1, rank1, h1p);
  // ---- B1 = twohop0[perm,perm]+I CSR + dinv1 (fused) ----
  k_build_B1<<<K1, 256, 0, stream>>>(rowptr, colidx, perm1, rank1, K1,
                                     dinv1, rowbeg1, rowend1, col1, val1, cursor);
  // ---- GCN1 (K1, sparse, relu) ----
  k_mm_dinv<<<(K1*32+TPB-1)/TPB, TPB, 0, stream>>>(h1p, W1, dinv1, hwd, K1, 32, 32);
  k_spmm_gcn<true><<<(K1*32+TPB-1)/TPB, TPB, 0, stream>>>(rowbeg1, rowend1, col1, val1, hwd, dinv1, b1, h1, K1);
  // ---- pool 2 ----
  k_pool_radix<1216><<<1, 1024, 0, stream>>>(h1, p1, K1, K2, perm2, rank2, h2p);
  // ---- two-hop level1 -> C2 + dinv2 (fused) ----
  k_twohop_sp<<<K2, 256, 0, stream>>>(rowbeg1, rowend1, col1, val1, perm2, rank2, C2, dinv2, K2);
  // ---- GCN2 (K2, dense row-block, relu) ----
  k_mm_dinv<<<(K2*32+TPB-1)/TPB, TPB, 0, stream>>>(h2p, W2, dinv2, hwd, K2, 32, 32);
  k_dgcn_row<true><<<K2, 256, 0, stream>>>(C2, hwd, dinv2, b2, h2, K2);
  // ---- pool 3 ----
  k_pool_radix<256><<<1, 1024, 0, stream>>>(h2, p2, K2, K3, perm3, rank3, h3p);
  // ---- two-hop level2 -> C3 + dinv3 (fused) ----
  k_gather_cols<<<(K2*K3+TPB-1)/TPB, TPB, 0, stream>>>(C2, K2, perm3, K3, Bp);
  k_twohop_d3  <<<K3, 256, 0, stream>>>(C2, K2, perm3, K3, Bp, C3, dinv3);
  // ---- GCN3 (K3, relu) ----
  k_mm_dinv<<<(K3*32+TPB-1)/TPB, TPB, 0, stream>>>(h3p, W3, dinv3, hwd, K3, 32, 32);
  k_dgcn_row<true><<<K3, 256, 0, stream>>>(C3, hwd, dinv3, b3, h3, K3);
  // ---- up 0 (level 2, relu) ----
  k_addup_mm<32><<<(K2*32+TPB-1)/TPB, TPB, 0, stream>>>(h2, h3, rank3, Wu0, dinv2, hwd, K2);
  k_dgcn_row<true><<<K2, 256, 0, stream>>>(C2, hwd, dinv2, bu0, hu2, K2);
  // ---- up 1 (level 1, sparse, relu) ----
  k_addup_mm<32><<<(K1*32+TPB-1)/TPB, TPB, 0, stream>>>(h1, hu2, rank2, Wu1, dinv1, hwd, K1);
  k_spmm_gcn<true><<<(K1*32+TPB-1)/TPB, TPB, 0, stream>>>(rowbeg1, rowend1, col1, val1, hwd, dinv1, bu1, hu1, K1);
  // ---- up 2 (level 0, 32->4, no relu) ----
  k_addup_mm<4><<<(n0*4+TPB-1)/TPB, TPB, 0, stream>>>(h0, hu1, rank1, Wu2, dinv0, hwd, n0);
  k_csr_gcn<4,false><<<(n0*4+TPB-1)/TPB, TPB, 0, stream>>>(rowptr, colidx, hwd, dinv0, bu2, out, n0);
  // ---- final BN + sigmoid on column 0 ----
  k_bn<<<1, 1024, 0, stream>>>(out, n0, bng, bnb);
}

// Round 4
// 246.072 us; speedup vs baseline: 4.5721x; 1.1751x over previous
//
#include <hip/hip_runtime.h>
#include <hip/hip_bf16.h>

#define TPB 256

// ---------------- CSR build (level 0 adjacency) ----------------
__global__ void k_count(const int* __restrict__ ei, int E, int* __restrict__ cnt){
  int e = blockIdx.x*blockDim.x + threadIdx.x;
  if(e < E) atomicAdd(&cnt[ei[E + e]], 1);   // rows = dst = edge_index[1]
}

// single-block scan, IPT elements per thread (1024 threads)
template<int IPT>
__global__ void k_scan(const int* __restrict__ cnt, int n, int* __restrict__ rowptr){
  int tid = threadIdx.x;
  int base = tid * IPT;
  int loc[IPT]; int s = 0;
  #pragma unroll
  for(int q = 0; q < IPT; ++q){ int i = base + q; int v = (i < n) ? cnt[i] : 0; s += v; loc[q] = s; }
  int lane = tid & 63, w = tid >> 6;
  int ss = s;
  #pragma unroll
  for(int o = 1; o < 64; o <<= 1){ int t = __shfl_up(ss, o, 64); if(lane >= o) ss += t; }
  __shared__ int wsum[16];
  if(lane == 63) wsum[w] = ss;
  __syncthreads();
  if(tid < 16){
    int t = wsum[tid];
    for(int o = 1; o < 16; o <<= 1){ int u = __shfl_up(t, o, 64); if(tid >= o) t += u; }
    wsum[tid] = t;
  }
  __syncthreads();
  int excl = ss - s + (w > 0 ? wsum[w-1] : 0);
  if(tid == 0) rowptr[0] = 0;
  #pragma unroll
  for(int q = 0; q < IPT; ++q){ int i = base + q; if(i < n) rowptr[i+1] = excl + loc[q]; }
}

__global__ void k_fill(const int* __restrict__ ei, int E, const int* __restrict__ rowptr,
                       int* __restrict__ fill, int* __restrict__ colidx){
  int e = blockIdx.x*blockDim.x + threadIdx.x;
  if(e >= E) return;
  int d = ei[E + e], s = ei[e];
  int p = rowptr[d] + atomicAdd(&fill[d], 1);
  colidx[p] = s;
}

// out[i][c] = dinv[i]*sum_d h[i][d]*W[d][c]; level0 variant computes dinv from cnt
// inline and emits it (c==0 lane) to dinv_out.
__global__ void k_mm_dinv(const float* __restrict__ h, const float* __restrict__ W,
                          const float* __restrict__ dinv, const int* __restrict__ cnt,
                          float* __restrict__ dinv_out, float* __restrict__ out,
                          int n, int cin, int cout){
  int t = blockIdx.x*blockDim.x + threadIdx.x;
  if(t >= n*cout) return;
  int i = t / cout, c = t - i*cout;
  float dv;
  if(cnt){ dv = rsqrtf((float)cnt[i] + 2.0f); if(c == 0) dinv_out[i] = dv; }
  else dv = dinv[i];
  float s = 0.f;
  for(int d = 0; d < cin; ++d) s += h[i*cin + d] * W[d*cout + c];
  out[t] = dv * s;
}

// fused unpool-add + weight GEMM: out = dinv[i] * ((base + scatter(h))·W)
template<int COUT>
__global__ void k_addup_mm(const float* __restrict__ base, const float* __restrict__ h,
                           const int* __restrict__ rank, const float* __restrict__ W,
                           const float* __restrict__ dinv, float* __restrict__ out, int n){
  int t = blockIdx.x*blockDim.x + threadIdx.x;
  if(t >= n*COUT) return;
  int i = t / COUT, c = t - i*COUT;
  int r = rank[i];
  const float* br = base + (size_t)i*32;
  const float* hr = h + (size_t)(r >= 0 ? r : 0)*32;
  float s = 0.f;
  #pragma unroll
  for(int d = 0; d < 32; ++d){
    float z = br[d] + ((r >= 0) ? hr[d] : 0.f);
    s += z * W[d*COUT + c];
  }
  out[t] = dinv[i] * s;
}

// y[i][c] = dinv[i]*( sum_{e:dst=i} xwd[src][c] + 2*xwd[i][c] ) + b[c]
// SCORE: also emit score[i] = tanh( (y_row · pvec) / |pvec| ) via width-32 shfl reduce
template<int C, bool RELU, bool SCORE>
__global__ void k_csr_gcn(const int* __restrict__ rowptr, const int* __restrict__ colidx,
                          const float* __restrict__ xwd, const float* __restrict__ dinv,
                          const float* __restrict__ bias, float* __restrict__ out, int n,
                          const float* __restrict__ pvec, float* __restrict__ score){
  int t = blockIdx.x*blockDim.x + threadIdx.x;
  if(t >= n*C) return;
  int i = t / C, c = t % C;
  float acc = 2.0f * xwd[i*C + c];
  int b = rowptr[i], e = rowptr[i+1];
  for(int p = b; p < e; ++p) acc += xwd[colidx[p]*C + c];
  float y = dinv[i]*acc + bias[c];
  y = RELU ? fmaxf(y, 0.f) : y;
  out[t] = y;
  if(SCORE){
    float pv = pvec[c];
    float sd = y*pv, nn = pv*pv;
    #pragma unroll
    for(int o = 16; o > 0; o >>= 1){ sd += __shfl_xor(sd, o, 32); nn += __shfl_xor(nn, o, 32); }
    if(c == 0) score[i] = tanhf(sd / sqrtf(nn));
  }
}

// fused: exact top-k via 3-pass MSD radix-select on 32-bit mapped scores ->
// tie-aware deterministic compaction (ties take lowest indices, matching
// jax.lax.top_k's selected SET) -> perm/rank/pooled h_out.
template<int NMAX>
__global__ __launch_bounds__(1024)
void k_pool_radix(const float* __restrict__ score, const float* __restrict__ h,
                  int n, int k, int* __restrict__ perm, int* __restrict__ rank,
                  float* __restrict__ hout){
  __shared__ unsigned keys[NMAX];
  __shared__ int bins[2048];
  __shared__ int wsum[16];
  __shared__ unsigned s_prefix;
  __shared__ int s_rk, s_found, s_cntgt;
  int tid = threadIdx.x, lane = tid & 63, w = tid >> 6;

  for(int i = tid; i < n; i += 1024){
    rank[i] = -1;
    unsigned u = __float_as_uint(score[i]);
    u ^= (u & 0x80000000u) ? 0xFFFFFFFFu : 0x80000000u;   // order-preserving map
    keys[i] = u;
  }
  if(tid == 0){ s_prefix = 0u; s_rk = k; }
  __syncthreads();

  // 3 MSD passes: widths 11,11,10 cover 32 bits
  for(int pass = 0; pass < 3; ++pass){
    const int width = (pass < 2) ? 11 : 10;
    const int shift = (pass == 0) ? 21 : ((pass == 1) ? 10 : 0);
    const int nb = 1 << width;
    for(int b2 = tid; b2 < nb; b2 += 1024) bins[b2] = 0;
    __syncthreads();
    unsigned prefix = s_prefix;
    int rk = s_rk;
    const int hs = shift + width;            // ==32 on pass 0 (guarded)
    for(int i = tid; i < n; i += 1024){
      unsigned kk = keys[i];
      bool match = (pass == 0) || ((kk >> hs) == (prefix >> hs));
      if(match) atomicAdd(&bins[(kk >> shift) & (nb-1)], 1);
    }
    __syncthreads();
    // suffix sums: bins[b] <- count of matching elems with digit >= b
    int ipt = (nb + 1023) >> 10;   // 2 or 1
    int loc0 = 0, loc1 = 0, s = 0;
    { int r = tid*ipt; int v = (r < nb) ? bins[nb-1-r] : 0; s += v; loc0 = s;
      if(ipt == 2){ int r2 = r+1; int v2 = (r2 < nb) ? bins[nb-1-r2] : 0; s += v2; loc1 = s; } }
    int ss = s;
    #pragma unroll
    for(int o = 1; o < 64; o <<= 1){ int t2 = __shfl_up(ss, o, 64); if(lane >= o) ss += t2; }
    if(lane == 63) wsum[w] = ss;
    __syncthreads();
    if(tid < 16){
      int t2 = wsum[tid];
      #pragma unroll
      for(int o = 1; o < 16; o <<= 1){ int u2 = __shfl_up(t2, o, 64); if(tid >= o) t2 += u2; }
      wsum[tid] = t2;
    }
    __syncthreads();
    int excl = ss - s + (w ? wsum[w-1] : 0);
    { int r = tid*ipt; if(r < nb) bins[nb-1-r] = excl + loc0;
      if(ipt == 2){ int r2 = r+1; if(r2 < nb) bins[nb-1-r2] = excl + loc1; } }
    __syncthreads();
    for(int b2 = tid; b2 < nb; b2 += 1024){
      int cge = bins[b2];
      int cgt = (b2+1 < nb) ? bins[b2+1] : 0;
      if(cge >= rk && cgt < rk){ s_found = b2; s_cntgt = cgt; }  // unique b2
    }
    __syncthreads();
    if(tid == 0){ s_prefix |= ((unsigned)s_found) << shift; s_rk -= s_cntgt; }
    __syncthreads();
  }
  unsigned T = s_prefix;        // k-th largest mapped score
  int r = s_rk;                 // ties to take (lowest indices first)
  int cgt_total = k - r;        // strictly-greater count

  // ordered compaction: '>' keys in index order -> slots [0,cgt); first r '=='
  // keys in index order -> slots [cgt, k)
  int CH = (n + 1023) >> 10;
  int base = tid*CH, c_gt = 0, c_eq = 0;
  for(int q = 0; q < CH; ++q){
    int i = base+q;
    if(i < n){ unsigned u = keys[i]; c_gt += (u > T); c_eq += (u == T); }
  }
  int packed = c_gt*8192 + c_eq;
  int ss2 = packed;
  #pragma unroll
  for(int o = 1; o < 64; o <<= 1){ int t2 = __shfl_up(ss2, o, 64); if(lane >= o) ss2 += t2; }
  if(lane == 63) wsum[w] = ss2;
  __syncthreads();
  if(tid < 16){
    int t2 = wsum[tid];
    #pragma unroll
    for(int o = 1; o < 16; o <<= 1){ int u2 = __shfl_up(t2, o, 64); if(tid >= o) t2 += u2; }
    wsum[tid] = t2;
  }
  __syncthreads();
  int excl2 = ss2 - packed + (w ? wsum[w-1] : 0);
  int gt_before = excl2 / 8192, eq_before = excl2 % 8192;
  for(int q = 0; q < CH; ++q){
    int i = base+q;
    if(i >= n) continue;
    unsigned u = keys[i];
    if(u > T){ int pos = gt_before++; perm[pos] = i; rank[i] = pos; }
    else if(u == T){
      int tr = eq_before++;
      if(tr < r){ int pos = cgt_total + tr; perm[pos] = i; rank[i] = pos; }
    }
  }
  __syncthreads();
  for(int t = tid; t < k*32; t += 1024){
    int i = t >> 5, c = t & 31;
    int idx = perm[i];
    hout[t] = h[(size_t)idx*32 + c] * score[idx];
  }
}

// Build B1 = twohop0(A)[perm,perm] + I directly as CSR (block per pooled row, LDS row).
// Also emits dinv1 = rsqrt(rowsum(C1)+2). Row bases via atomic cursor (contents per
// row deterministic -> downstream output deterministic).
__global__ __launch_bounds__(256)
void k_build_B1(const int* __restrict__ rowptr, const int* __restrict__ colidx,
                const int* __restrict__ perm1, const int* __restrict__ rank1, int K1,
                float* __restrict__ dinv1, int* __restrict__ rowbeg, int* __restrict__ rowend,
                int* __restrict__ col1, float* __restrict__ val1, int* __restrict__ cursor){
  __shared__ float row[1216];
  __shared__ int wsum[4];
  __shared__ float fs[4];
  __shared__ int s_base;
  int tid = threadIdx.x, lane = tid & 63, w = tid >> 6;
  int i = blockIdx.x;
  for(int j = tid; j < K1; j += 256) row[j] = 0.f;
  __syncthreads();
  int d = perm1[i];
  int b = rowptr[d], len = rowptr[d+1]-b;
  for(int p = tid; p < len; p += 256){
    int s = colidx[b+p]; int rs = rank1[s];
    if(rs >= 0) atomicAdd(&row[rs], 2.0f);          // 2A term
  }
  for(int ww = tid; ww < len*8; ww += 256){
    int p = ww >> 3, sub = ww & 7;
    int s = colidx[b+p];
    for(int q = rowptr[s]+sub, qe = rowptr[s+1]; q < qe; q += 8){
      int r2 = rank1[colidx[q]];
      if(r2 >= 0) atomicAdd(&row[r2], 1.0f);        // A^2 (2-path) term
    }
  }
  __syncthreads();
  if(tid == 0) row[i] = 0.f;                        // diag <- 0
  __syncthreads();
  float s = 0.f;
  for(int j = tid; j < K1; j += 256) s += row[j];
  for(int o = 32; o > 0; o >>= 1) s += __shfl_down(s, o, 64);
  if(lane == 0) fs[w] = s;
  __syncthreads();
  if(tid == 0){
    dinv1[i] = rsqrtf(fs[0]+fs[1]+fs[2]+fs[3] + 2.0f);
    row[i] = 1.0f;                                  // +I for B1
  }
  __syncthreads();
  int CH = (K1 + 255) >> 8;
  int base = tid*CH, cnt = 0;
  for(int q = 0; q < CH; ++q){ int j = base+q; if(j < K1 && row[j] != 0.f) ++cnt; }
  int ss = cnt;
  #pragma unroll
  for(int o = 1; o < 64; o <<= 1){ int t2 = __shfl_up(ss, o, 64); if(lane >= o) ss += t2; }
  if(lane == 63) wsum[w] = ss;
  __syncthreads();
  if(tid < 4){
    int t2 = wsum[tid];
    for(int o = 1; o < 4; o <<= 1){ int u2 = __shfl_up(t2, o, 64); if(tid >= o) t2 += u2; }
    wsum[tid] = t2;
  }
  __syncthreads();
  if(tid == 0) s_base = atomicAdd(cursor, wsum[3]);
  __syncthreads();
  int off = s_base + ss - cnt + (w ? wsum[w-1] : 0);
  for(int q = 0; q < CH; ++q){
    int j = base+q;
    if(j < K1 && row[j] != 0.f){ col1[off] = j; val1[off] = row[j]; ++off; }
  }
  if(tid == 0){ rowbeg[i] = s_base; rowend[i] = s_base + wsum[3]; }
}

// SpMM GCN over B1-CSR: y = dinv[i]*( hwd[i] + sum_p val*hwd[col] ) + b  (Ah = B1+I)
template<bool RELU, bool SCORE>
__global__ void k_spmm_gcn(const int* __restrict__ rb, const int* __restrict__ re,
                           const int* __restrict__ ci, const float* __restrict__ cv,
                           const float* __restrict__ hwd, const float* __restrict__ dinv,
                           const float* __restrict__ bias, float* __restrict__ out, int n,
                           const float* __restrict__ pvec, float* __restrict__ score){
  int t = blockIdx.x*blockDim.x + threadIdx.x;
  if(t >= n*32) return;
  int i = t >> 5, c = t & 31;
  float acc = hwd[i*32 + c];
  for(int p = rb[i], e = re[i]; p < e; ++p) acc += cv[p]*hwd[ci[p]*32 + c];
  float y = dinv[i]*acc + bias[c];
  y = RELU ? fmaxf(y, 0.f) : y;
  out[t] = y;
  if(SCORE){
    float pv = pvec[c];
    float sd = y*pv, nn = pv*pv;
    #pragma unroll
    for(int o = 16; o > 0; o >>= 1){ sd += __shfl_xor(sd, o, 32); nn += __shfl_xor(nn, o, 32); }
    if(c == 0) score[i] = tanhf(sd / sqrtf(nn));
  }
}

// C2 = B1^2 [perm2][:,perm2], diag<-0, via sparse path enumeration; also emits dinv2
__global__ __launch_bounds__(256)
void k_twohop_sp(const int* __restrict__ rb, const int* __restrict__ re,
                 const int* __restrict__ ci, const float* __restrict__ cv,
                 const int* __restrict__ perm2, const int* __restrict__ rank2,
                 float* __restrict__ C2, float* __restrict__ dinv2, int K2){
  __shared__ float acc[256];
  __shared__ float fs[4];
  int i = blockIdx.x, tid = threadIdx.x, lane = tid & 63, w = tid >> 6;
  for(int j = tid; j < K2; j += 256) acc[j] = 0.f;
  __syncthreads();
  int qi = perm2[i];
  int b = rb[qi], len = re[qi]-b;
  for(int ww = tid; ww < len*8; ww += 256){
    int p = b + (ww >> 3), sub = ww & 7;
    int t = ci[p]; float v = cv[p];
    for(int q = rb[t] + sub, qe = re[t]; q < qe; q += 8){
      int j = rank2[ci[q]];
      if(j >= 0) atomicAdd(&acc[j], v*cv[q]);   // exact integer adds
    }
  }
  __syncthreads();
  if(tid == 0) acc[i] = 0.f;
  __syncthreads();
  float s = 0.f;
  for(int j = tid; j < K2; j += 256) s += acc[j];
  for(int o = 32; o > 0; o >>= 1) s += __shfl_down(s, o, 64);
  if(lane == 0) fs[w] = s;
  __syncthreads();
  if(tid == 0) dinv2[i] = rsqrtf(fs[0]+fs[1]+fs[2]+fs[3] + 2.0f);
  for(int j = tid; j < K2; j += 256) C2[(size_t)i*K2 + j] = acc[j];
}

// dense GCN, block-per-row, 8-way K-split + LDS reduce; optional fused score
template<bool RELU, bool SCORE>
__global__ void k_dgcn_row(const float* __restrict__ C, const float* __restrict__ hwd,
                           const float* __restrict__ dinv, const float* __restrict__ bias,
                           float* __restrict__ out, int n,
                           const float* __restrict__ pvec, float* __restrict__ score){
  __shared__ float sh[8][32];
  int i = blockIdx.x;
  int c = threadIdx.x & 31, s = threadIdx.x >> 5;
  const float* row = C + (size_t)i*n;
  float acc = 0.f;
  for(int t = s; t < n; t += 8) acc += row[t]*hwd[t*32 + c];
  sh[s][c] = acc;
  __syncthreads();
  if(s == 0){
    float a = sh[0][c]+sh[1][c]+sh[2][c]+sh[3][c]+sh[4][c]+sh[5][c]+sh[6][c]+sh[7][c];
    a += 2.f*hwd[i*32 + c];
    float y = dinv[i]*a + bias[c];
    y = RELU ? fmaxf(y, 0.f) : y;
    out[i*32 + c] = y;
    if(SCORE){
      float pv = pvec[c];
      float sd = y*pv, nn = pv*pv;
      #pragma unroll
      for(int o = 16; o > 0; o >>= 1){ sd += __shfl_xor(sd, o, 32); nn += __shfl_xor(nn, o, 32); }
      if(c == 0) score[i] = tanhf(sd / sqrtf(nn));
    }
  }
}

// level-2 two-hop (fused column gather): C3[i][j] = sum_t (C2[qi][t]+I)*(C2[t][qj]+I),
// diag<-0; also emits dinv3
__global__ __launch_bounds__(256)
void k_twohop_d3(const float* __restrict__ C2, int n, const int* __restrict__ perm3,
                 int k, float* __restrict__ C3, float* __restrict__ dinv3){
  __shared__ float acc[4][64];
  int i = blockIdx.x, tid = threadIdx.x;
  int col = tid & 63, st = tid >> 6;
  int qi = perm3[i];
  int qj = (col < k) ? perm3[col] : 0;
  float a = 0.f;
  if(col < k){
    for(int tt = st; tt < n; tt += 4){
      float av = C2[(size_t)qi*n + tt] + ((tt == qi) ? 1.f : 0.f);
      float bv = C2[(size_t)tt*n + qj] + ((tt == qj) ? 1.f : 0.f);
      a += av * bv;
    }
  }
  acc[st][col] = a;
  __syncthreads();
  if(st == 0){
    float v = acc[0][col]+acc[1][col]+acc[2][col]+acc[3][col];
    if(col == i) v = 0.f;
    if(col < k) C3[(size_t)i*k + col] = v;
    float sv = (col < k) ? v : 0.f;
    for(int o = 32; o > 0; o >>= 1) sv += __shfl_down(sv, o, 64);
    if(col == 0) dinv3[i] = rsqrtf(sv + 2.0f);
  }
}

__global__ void k_bn(float* __restrict__ out, int n, const float* __restrict__ g,
                     const float* __restrict__ b){
  __shared__ float sh[16];
  __shared__ float sval;
  int tid = threadIdx.x, lane = tid & 63, w = tid >> 6;
  int nw = blockDim.x >> 6;
  float s = 0.f;
  for(int i = tid; i < n; i += blockDim.x) s += out[i*4];
  for(int o = 32; o > 0; o >>= 1) s += __shfl_down(s, o, 64);
  if(lane == 0) sh[w] = s;
  __syncthreads();
  if(tid == 0){ float t = 0.f; for(int q = 0; q < nw; ++q) t += sh[q]; sval = t / n; }
  __syncthreads();
  float mean = sval;
  float v = 0.f;
  for(int i = tid; i < n; i += blockDim.x){ float d = out[i*4] - mean; v += d*d; }
  for(int o = 32; o > 0; o >>= 1) v += __shfl_down(v, o, 64);
  __syncthreads();
  if(lane == 0) sh[w] = v;
  __syncthreads();
  if(tid == 0){ float t = 0.f; for(int q = 0; q < nw; ++q) t += sh[q]; sval = t / n; }
  __syncthreads();
  float var = sval;
  float scale = g[0] * rsqrtf(var + 1e-5f);
  float beta = b[0];
  for(int i = tid; i < n; i += blockDim.x){
    float r = scale*(out[i*4] - mean) + beta;
    out[i*4] = 1.f / (1.f + expf(-r));
  }
}

extern "C" void kernel_launch(void* const* d_in, const int* in_sizes, int n_in,
                              void* d_out, int out_size, void* d_ws, size_t ws_size,
                              hipStream_t stream){
  const float* x  =(const float*)d_in[0];
  const int*   ei =(const int*)  d_in[1];
  const float* W0 =(const float*)d_in[2];  const float* b0 =(const float*)d_in[3];
  const float* W1 =(const float*)d_in[4];  const float* b1 =(const float*)d_in[5];
  const float* W2 =(const float*)d_in[6];  const float* b2 =(const float*)d_in[7];
  const float* W3 =(const float*)d_in[8];  const float* b3 =(const float*)d_in[9];
  const float* p0 =(const float*)d_in[10];
  const float* p1 =(const float*)d_in[11];
  const float* p2 =(const float*)d_in[12];
  const float* Wu0=(const float*)d_in[13]; const float* bu0=(const float*)d_in[14];
  const float* Wu1=(const float*)d_in[15]; const float* bu1=(const float*)d_in[16];
  const float* Wu2=(const float*)d_in[17]; const float* bu2=(const float*)d_in[18];
  const float* bng=(const float*)d_in[19]; const float* bnb=(const float*)d_in[20];
  float* out = (float*)d_out;

  const int n0 = in_sizes[0] / 3;       // 6000
  const int E  = in_sizes[1] / 2;       // 96000
  const int K1 = (n0 + 4) / 5;          // 1200
  const int K2 = (K1 + 4) / 5;          // 240
  const int K3 = (K2 + 4) / 5;          // 48
  const int CAP1 = 512*1024;            // B1-CSR capacity (expected ~70K nnz)

  char* wsp = (char*)d_ws; size_t off = 0;
  auto alloc = [&](size_t bytes)->char*{
    char* p = wsp + off; off = (off + bytes + 255) & ~((size_t)255); return p;
  };

  // zeroed region: cnt | fill | cursor (single memset)
  int*   zreg   = (int*)  alloc((size_t)(2*n0+64)*4);
  int*   cnt    = zreg;
  int*   fill   = zreg + n0;
  int*   cursor = zreg + 2*n0;
  int*   rowptr = (int*)  alloc((size_t)(n0+1)*4);
  int*   colidx = (int*)  alloc((size_t)E*4);
  float* dinv0  = (float*)alloc((size_t)n0*4);
  float* hwd    = (float*)alloc((size_t)n0*32*4);
  float* h0     = (float*)alloc((size_t)n0*32*4);
  float* score  = (float*)alloc((size_t)n0*4);
  int*   perm1  = (int*)  alloc((size_t)K1*4);
  int*   rank1  = (int*)  alloc((size_t)n0*4);
  float* h1p    = (float*)alloc((size_t)K1*32*4);
  float* dinv1  = (float*)alloc((size_t)K1*4);
  int*   rowbeg1= (int*)  alloc((size_t)K1*4);
  int*   rowend1= (int*)  alloc((size_t)K1*4);
  int*   col1   = (int*)  alloc((size_t)CAP1*4);
  float* val1   = (float*)alloc((size_t)CAP1*4);
  float* h1     = (float*)alloc((size_t)K1*32*4);
  int*   perm2  = (int*)  alloc((size_t)K2*4);
  int*   rank2  = (int*)  alloc((size_t)K1*4);
  float* h2p    = (float*)alloc((size_t)K2*32*4);
  float* C2     = (float*)alloc((size_t)K2*K2*4);
  float* dinv2  = (float*)alloc((size_t)K2*4);
  float* h2     = (float*)alloc((size_t)K2*32*4);
  int*   perm3  = (int*)  alloc((size_t)K3*4);
  int*   rank3  = (int*)  alloc((size_t)K2*4);
  float* h3p    = (float*)alloc((size_t)K3*32*4);
  float* C3     = (float*)alloc((size_t)K3*K3*4);
  float* dinv3  = (float*)alloc((size_t)K3*4);
  float* h3     = (float*)alloc((size_t)K3*32*4);
  float* hu2    = (float*)alloc((size_t)K2*32*4);
  float* hu1    = (float*)alloc((size_t)K1*32*4);

  hipMemsetAsync(zreg, 0, (size_t)(2*n0+64)*4, stream);

  const int gE = (E + TPB - 1) / TPB;
  // ---- CSR0 ----
  k_count  <<<gE, TPB, 0, stream>>>(ei, E, cnt);
  k_scan<6><<<1, 1024, 0, stream>>>(cnt, n0, rowptr);
  k_fill   <<<gE, TPB, 0, stream>>>(ei, E, rowptr, fill, colidx);
  // ---- GCN0 (n0, 3->32, relu) + fused dinv0 + fused score ----
  k_mm_dinv<<<(n0*32+TPB-1)/TPB, TPB, 0, stream>>>(x, W0, nullptr, cnt, dinv0, hwd, n0, 3, 32);
  k_csr_gcn<32,true,true><<<(n0*32+TPB-1)/TPB, TPB, 0, stream>>>(rowptr, colidx, hwd, dinv0, b0, h0, n0, p0, score);
  // ---- pool 1 ----
  k_pool_radix<6144><<<1, 1024, 0, stream>>>(score, h0, n0, K1, perm1, rank1, h1p);
  // ---- B1 = twohop0[perm,perm]+I CSR + dinv1 (fused) ----
  k_build_B1<<<K1, 256, 0, stream>>>(rowptr, colidx, perm1, rank1, K1,
                                     dinv1, rowbeg1, rowend1, col1, val1, cursor);
  // ---- GCN1 (K1, sparse, relu) + fused score ----
  k_mm_dinv<<<(K1*32+TPB-1)/TPB, TPB, 0, stream>>>(h1p, W1, dinv1, nullptr, nullptr, hwd, K1, 32, 32);
  k_spmm_gcn<true,true><<<(K1*32+TPB-1)/TPB, TPB, 0, stream>>>(rowbeg1, rowend1, col1, val1, hwd, dinv1, b1, h1, K1, p1, score);
  // ---- pool 2 ----
  k_pool_radix<1216><<<1, 1024, 0, stream>>>(score, h1, K1, K2, perm2, rank2, h2p);
  // ---- two-hop level1 -> C2 + dinv2 (fused) ----
  k_twohop_sp<<<K2, 256, 0, stream>>>(rowbeg1, rowend1, col1, val1, perm2, rank2, C2, dinv2, K2);
  // ---- GCN2 (K2, dense row-block, relu) + fused score ----
  k_mm_dinv<<<(K2*32+TPB-1)/TPB, TPB, 0, stream>>>(h2p, W2, dinv2, nullptr, nullptr, hwd, K2, 32, 32);
  k_dgcn_row<true,true><<<K2, 256, 0, stream>>>(C2, hwd, dinv2, b2, h2, K2, p2, score);
  // ---- pool 3 ----
  k_pool_radix<256><<<1, 1024, 0, stream>>>(score, h2, K2, K3, perm3, rank3, h3p);
  // ---- two-hop level2 -> C3 + dinv3 (fused gather) ----
  k_twohop_d3<<<K3, 256, 0, stream>>>(C2, K2, perm3, K3, C3, dinv3);
  // ---- GCN3 (K3, relu) ----
  k_mm_dinv<<<(K3*32+TPB-1)/TPB, TPB, 0, stream>>>(h3p, W3, dinv3, nullptr, nullptr, hwd, K3, 32, 32);
  k_dgcn_row<true,false><<<K3, 256, 0, stream>>>(C3, hwd, dinv3, b3, h3, K3, nullptr, nullptr);
  // ---- up 0 (level 2, relu) ----
  k_addup_mm<32><<<(K2*32+TPB-1)/TPB, TPB, 0, stream>>>(h2, h3, rank3, Wu0, dinv2, hwd, K2);
  k_dgcn_row<true,false><<<K2, 256, 0, stream>>>(C2, hwd, dinv2, bu0, hu2, K2, nullptr, nullptr);
  // ---- up 1 (level 1, sparse, relu) ----
  k_addup_mm<32><<<(K1*32+TPB-1)/TPB, TPB, 0, stream>>>(h1, hu2, rank2, Wu1, dinv1, hwd, K1);
  k_spmm_gcn<true,false><<<(K1*32+TPB-1)/TPB, TPB, 0, stream>>>(rowbeg1, rowend1, col1, val1, hwd, dinv1, bu1, hu1, K1, nullptr, nullptr);
  // ---- up 2 (level 0, 32->4, no relu) ----
  k_addup_mm<4><<<(n0*4+TPB-1)/TPB, TPB, 0, stream>>>(h0, hu1, rank1, Wu2, dinv0, hwd, n0);
  k_csr_gcn<4,false,false><<<(n0*4+TPB-1)/TPB, TPB, 0, stream>>>(rowptr, colidx, hwd, dinv0, bu2, out, n0, nullptr, nullptr);
  // ---- final BN + sigmoid on column 0 ----
  k_bn<<<1, 1024, 0, stream>>>(out, n0, bng, bnb);
}